// Round 1
// baseline (789.087 us; speedup 1.0000x reference)
//
#include <hip/hip_runtime.h>
#include <cstddef>

__device__ __forceinline__ float sigmoidf_(float x){ return 1.0f/(1.0f + __expf(-x)); }

// ---------------- generic transpose (tiny weights only) ----------------
__global__ void ktrans(const float* __restrict__ src, float* __restrict__ dst, int R, int C)
{
    int idx = blockIdx.x*256 + threadIdx.x;
    if (idx < R*C){ int r = idx / C; int c = idx - r*C; dst[c*R + r] = src[idx]; }
}

// ---------------- stage 1 (per batch): gather emb, hv_in/out, bmm -> inputs ----------------
// block = 256 threads, grid = Bc (chunk batches)
__global__ __launch_bounds__(256) void k_gnn_stage1(
    const int* __restrict__ items, const float* __restrict__ Amat,
    const float* __restrict__ emb,
    const float* __restrict__ W_in, const float* __restrict__ b_in,
    const float* __restrict__ W_out, const float* __restrict__ b_out,
    const float* __restrict__ b_iah, const float* __restrict__ b_oah,
    float* __restrict__ hidden, float* __restrict__ inputs, int b0)
{
    const int t = threadIdx.x;
    const int lane = t & 63;
    const int w = t >> 6;
    const int bl = blockIdx.x;
    const int b = b0 + bl;

    __shared__ float s_hid[64][132];
    __shared__ float s_A[64][132];
    __shared__ float s_hvT[256][65];
    __shared__ int s_items[64];

    if (t < 64) s_items[t] = items[b*64 + t];
    __syncthreads();

    const float* Ab = Amat + (size_t)b * 8192;
    #pragma unroll
    for (int c = 0; c < 8; ++c){
        int flat = c*1024 + t*4;
        int n = flat >> 7, h = flat & 127;
        float4 v = *(const float4*)(emb + (size_t)s_items[n]*128 + h);
        *(float4*)&s_hid[n][h] = v;
        *(float4*)(hidden + (size_t)(bl*64 + n)*128 + h) = v;
        *(float4*)&s_A[n][h] = *(const float4*)(Ab + flat);
    }
    __syncthreads();

    // hv: row n = lane; wave w computes cols j = w*64 + jj  (j<128 -> W_in, else W_out)
    {
        const int n = lane;
        float hrow[128];
        #pragma unroll
        for (int k = 0; k < 128; ++k) hrow[k] = s_hid[n][k];
        const float* Wsel = (w < 2) ? (W_in + (size_t)(w*64)*128) : (W_out + (size_t)((w-2)*64)*128);
        const float* bsel = (w < 2) ? (b_in + w*64) : (b_out + (w-2)*64);
        for (int jj = 0; jj < 64; ++jj){
            const float* Wr = Wsel + (size_t)jj*128;
            float a0 = bsel[jj], a1 = 0.f, a2 = 0.f, a3 = 0.f;
            #pragma unroll
            for (int k = 0; k < 128; k += 4){
                float4 wv = *(const float4*)(Wr + k);
                a0 += hrow[k+0]*wv.x;
                a1 += hrow[k+1]*wv.y;
                a2 += hrow[k+2]*wv.z;
                a3 += hrow[k+3]*wv.w;
            }
            s_hvT[w*64 + jj][n] = (a0+a1)+(a2+a3);
        }
    }
    __syncthreads();

    // bmm: wave w handles rows n in [w*16, w*16+16); col j = lane-based
    {
        float acc0[16], acc1[16];
        // ---- pass "in": cols j=lane and 64+lane, A cols m in [0,64)
        #pragma unroll
        for (int ni = 0; ni < 16; ++ni){ acc0[ni] = b_iah[lane]; acc1[ni] = b_iah[64+lane]; }
        for (int m = 0; m < 64; ++m){
            float hv0 = s_hvT[lane][m];
            float hv1 = s_hvT[64+lane][m];
            #pragma unroll
            for (int ni = 0; ni < 16; ++ni){
                float av = s_A[w*16+ni][m];
                acc0[ni] += av*hv0;
                acc1[ni] += av*hv1;
            }
        }
        #pragma unroll
        for (int ni = 0; ni < 16; ++ni){
            size_t rr = (size_t)(bl*64 + w*16 + ni)*256;
            inputs[rr + lane]    = acc0[ni];
            inputs[rr + 64+lane] = acc1[ni];
        }
        // ---- pass "out": cols j=128+lane and 192+lane, A cols m in [64,128)
        #pragma unroll
        for (int ni = 0; ni < 16; ++ni){ acc0[ni] = b_oah[lane]; acc1[ni] = b_oah[64+lane]; }
        for (int m = 0; m < 64; ++m){
            float hv0 = s_hvT[128+lane][m];
            float hv1 = s_hvT[192+lane][m];
            #pragma unroll
            for (int ni = 0; ni < 16; ++ni){
                float av = s_A[w*16+ni][64+m];
                acc0[ni] += av*hv0;
                acc1[ni] += av*hv1;
            }
        }
        #pragma unroll
        for (int ni = 0; ni < 16; ++ni){
            size_t rr = (size_t)(bl*64 + w*16 + ni)*256;
            inputs[rr + 128+lane] = acc0[ni];
            inputs[rr + 192+lane] = acc1[ni];
        }
    }
}

// ---------------- generic GEMM: C[M][N] = A[M][K] @ Bt[K][N] + bias[N] ----------------
// block tile: 64 rows x 128 cols, 256 threads, thread tile 8x4.
// grid: (N/128, M/64).  M%64==0, N%128==0, K%32==0 required.
__global__ __launch_bounds__(256) void k_gemm(
    const float* __restrict__ A, const float* __restrict__ Bt,
    const float* __restrict__ bias, float* __restrict__ C,
    int M, int N, int K)
{
    const int t = threadIdx.x;
    const int tc = t & 31, tr = t >> 5;
    const int rb = blockIdx.y * 64;
    const int cb = blockIdx.x * 128;

    __shared__ float As[64][36];
    __shared__ float Ws[32][132];

    float acc[8][4];
    {
        float4 bv = *(const float4*)(bias + cb + tc*4);
        #pragma unroll
        for (int i = 0; i < 8; ++i){ acc[i][0]=bv.x; acc[i][1]=bv.y; acc[i][2]=bv.z; acc[i][3]=bv.w; }
    }

    for (int kc = 0; kc < K; kc += 32){
        // load A tile to regs: each thread 1 row, 8 floats
        int arow = t >> 2;
        int ak0  = (t & 3) * 8;
        const float* asrc = A + (size_t)(rb + arow)*K + kc + ak0;
        float4 av0 = *(const float4*)(asrc);
        float4 av1 = *(const float4*)(asrc + 4);
        // load W tile to regs: k = t>>3, 16 cols
        int wk  = t >> 3;
        int wc0 = (t & 7) * 16;
        const float* wsrc = Bt + (size_t)(kc + wk)*N + cb + wc0;
        float4 wv0 = *(const float4*)(wsrc);
        float4 wv1 = *(const float4*)(wsrc + 4);
        float4 wv2 = *(const float4*)(wsrc + 8);
        float4 wv3 = *(const float4*)(wsrc + 12);
        __syncthreads();
        *(float4*)&As[arow][ak0]   = av0;
        *(float4*)&As[arow][ak0+4] = av1;
        *(float4*)&Ws[wk][wc0]     = wv0;
        *(float4*)&Ws[wk][wc0+4]   = wv1;
        *(float4*)&Ws[wk][wc0+8]   = wv2;
        *(float4*)&Ws[wk][wc0+12]  = wv3;
        __syncthreads();
        #pragma unroll
        for (int k = 0; k < 32; ++k){
            float4 wv = *(const float4*)&Ws[k][tc*4];
            #pragma unroll
            for (int i = 0; i < 8; ++i){
                float a_ = As[tr*8+i][k];
                acc[i][0] += a_*wv.x; acc[i][1] += a_*wv.y;
                acc[i][2] += a_*wv.z; acc[i][3] += a_*wv.w;
            }
        }
    }
    #pragma unroll
    for (int i = 0; i < 8; ++i){
        float4 o; o.x=acc[i][0]; o.y=acc[i][1]; o.z=acc[i][2]; o.w=acc[i][3];
        *(float4*)(C + (size_t)(rb + tr*8 + i)*N + cb + tc*4) = o;
    }
}

// ---------------- GRU gate fuse ----------------
__global__ __launch_bounds__(256) void k_gate(
    const float* __restrict__ gi, const float* __restrict__ gh,
    const float* __restrict__ hid, float* __restrict__ outp, int M)
{
    int q = blockIdx.x*256 + threadIdx.x;
    if (q >= M*32) return;
    int r = q >> 5, h4 = (q & 31) << 2;
    const float* gir = gi + (size_t)r*384;
    const float* ghr = gh + (size_t)r*384;
    float4 xr = *(const float4*)(gir + h4);
    float4 yr = *(const float4*)(ghr + h4);
    float4 xi = *(const float4*)(gir + 128 + h4);
    float4 yi = *(const float4*)(ghr + 128 + h4);
    float4 xn = *(const float4*)(gir + 256 + h4);
    float4 yn = *(const float4*)(ghr + 256 + h4);
    float4 hv = *(const float4*)(hid + (size_t)r*128 + h4);
    float4 o;
    {
        float rg, ig, ng;
        rg = sigmoidf_(xr.x+yr.x); ig = sigmoidf_(xi.x+yi.x); ng = tanhf(xn.x + rg*yn.x); o.x = ng + ig*(hv.x - ng);
        rg = sigmoidf_(xr.y+yr.y); ig = sigmoidf_(xi.y+yi.y); ng = tanhf(xn.y + rg*yn.y); o.y = ng + ig*(hv.y - ng);
        rg = sigmoidf_(xr.z+yr.z); ig = sigmoidf_(xi.z+yi.z); ng = tanhf(xn.z + rg*yn.z); o.z = ng + ig*(hv.z - ng);
        rg = sigmoidf_(xr.w+yr.w); ig = sigmoidf_(xi.w+yi.w); ng = tanhf(xn.w + rg*yn.w); o.w = ng + ig*(hv.w - ng);
    }
    *(float4*)(outp + (size_t)r*128 + h4) = o;
}

// ---------------- seq: gather + [pos|seq]@linear_pos + tanh + l2norm; also ht & q1 ----------------
__global__ __launch_bounds__(256) void k_seq(
    const int* __restrict__ alias, const float* __restrict__ pos,
    const float* __restrict__ lp, const float* __restrict__ hn,
    const float* __restrict__ W1, const float* __restrict__ b1,
    float* __restrict__ seq, float* __restrict__ ht, float* __restrict__ q1,
    int b0)
{
    const int t = threadIdx.x;
    const int bl = blockIdx.x, b = b0 + bl;
    __shared__ float Xs[64][260];
    __shared__ float Ys[64][132];
    __shared__ int s_alias[64];
    __shared__ float s_rn[64];
    __shared__ int s_last;

    if (t < 64) s_alias[t] = alias[b*64 + t];
    __syncthreads();
    if (t == 0){
        int cnt = 0;
        for (int l = 0; l < 64; ++l) cnt += (s_alias[l] > 0) ? 1 : 0;
        s_last = (cnt - 1) & 63;
    }
    #pragma unroll
    for (int c = 0; c < 8; ++c){
        int flat = c*1024 + t*4;
        int l = flat >> 7, k = flat & 127;
        *(float4*)&Xs[l][k] = *(const float4*)(pos + l*128 + k);
        int row = s_alias[l];
        *(float4*)&Xs[l][128+k] = *(const float4*)(hn + (size_t)(bl*64 + row)*128 + k);
    }
    __syncthreads();

    const int tc = t & 31, tr = t >> 5;
    float acc[8][4];
    #pragma unroll
    for (int i=0;i<8;i++){ acc[i][0]=0.f; acc[i][1]=0.f; acc[i][2]=0.f; acc[i][3]=0.f; }

    for (int k = 0; k < 256; k += 4){
        float4 w0 = *(const float4*)(lp + (size_t)(k+0)*128 + tc*4);
        float4 w1 = *(const float4*)(lp + (size_t)(k+1)*128 + tc*4);
        float4 w2 = *(const float4*)(lp + (size_t)(k+2)*128 + tc*4);
        float4 w3 = *(const float4*)(lp + (size_t)(k+3)*128 + tc*4);
        #pragma unroll
        for (int i = 0; i < 8; ++i){
            float4 a4 = *(const float4*)&Xs[tr*8+i][k];
            acc[i][0] += a4.x*w0.x + a4.y*w1.x + a4.z*w2.x + a4.w*w3.x;
            acc[i][1] += a4.x*w0.y + a4.y*w1.y + a4.z*w2.y + a4.w*w3.y;
            acc[i][2] += a4.x*w0.z + a4.y*w1.z + a4.z*w2.z + a4.w*w3.z;
            acc[i][3] += a4.x*w0.w + a4.y*w1.w + a4.z*w2.w + a4.w*w3.w;
        }
    }
    #pragma unroll
    for (int i = 0; i < 8; ++i){
        float4 o;
        o.x = tanhf(acc[i][0]); o.y = tanhf(acc[i][1]);
        o.z = tanhf(acc[i][2]); o.w = tanhf(acc[i][3]);
        *(float4*)&Ys[tr*8+i][tc*4] = o;
    }
    __syncthreads();
    if (t < 64){
        float s = 0.f;
        #pragma unroll 8
        for (int k = 0; k < 128; ++k){ float v = Ys[t][k]; s = fmaf(v, v, s); }
        s_rn[t] = rsqrtf(s);
    }
    __syncthreads();
    #pragma unroll
    for (int c = 0; c < 8; ++c){
        int flat = c*1024 + t*4;
        int l = flat >> 7, k = flat & 127;
        float rn = s_rn[l];
        float4 o;
        o.x = Ys[l][k+0]*rn; o.y = Ys[l][k+1]*rn; o.z = Ys[l][k+2]*rn; o.w = Ys[l][k+3]*rn;
        *(float4*)(seq + (size_t)(bl*64 + l)*128 + k) = o;
    }
    if (t < 128){
        int h = t;
        int lst = s_last;
        float rn = s_rn[lst];
        float hv = Ys[lst][h]*rn;
        ht[(size_t)b*128 + h] = hv;
        float o = b1[h];
        const float* wr = W1 + (size_t)h*128;
        #pragma unroll 8
        for (int k = 0; k < 128; ++k) o += (Ys[lst][k]*rn) * wr[k];
        q1[(size_t)b*128 + h] = o;
    }
}

// ---------------- attention + final projection a_final ----------------
__global__ __launch_bounds__(256) void k_attn(
    const int* __restrict__ alias, const float* __restrict__ seq,
    const float* __restrict__ q2m, const float* __restrict__ q1,
    const float* __restrict__ ht, const float* __restrict__ W3,
    const float* __restrict__ Wt, const float* __restrict__ bt,
    float* __restrict__ afin, int b0)
{
    const int t = threadIdx.x;
    const int bl = blockIdx.x, b = b0 + bl;
    __shared__ float s_seq[64][132];
    __shared__ float s_q2[64][132];
    __shared__ float s_q1[128], s_ht[128];
    __shared__ float s_part[64][4];
    __shared__ float s_alpha[64];
    __shared__ float s_a[128];
    __shared__ int s_alias2[64];

    if (t < 64) s_alias2[t] = alias[b*64 + t];
    if (t < 128){ s_q1[t] = q1[(size_t)b*128 + t]; s_ht[t] = ht[(size_t)b*128 + t]; }
    #pragma unroll
    for (int c = 0; c < 8; ++c){
        int flat = c*1024 + t*4;
        int l = flat >> 7, k = flat & 127;
        *(float4*)&s_seq[l][k] = *(const float4*)(seq + (size_t)(bl*64 + l)*128 + k);
        *(float4*)&s_q2[l][k]  = *(const float4*)(q2m + (size_t)(bl*64 + l)*128 + k);
    }
    __syncthreads();
    {
        int l = t >> 2, g = t & 3;
        float p = 0.f;
        #pragma unroll 8
        for (int hh = 0; hh < 32; ++hh){
            int h = g*32 + hh;
            float sv = sigmoidf_(s_q1[h] + s_q2[l][h]);
            p += sv * W3[h];
        }
        s_part[l][g] = p;
    }
    __syncthreads();
    if (t < 64){
        float al = s_part[t][0] + s_part[t][1] + s_part[t][2] + s_part[t][3];
        s_alpha[t] = (s_alias2[t] > 0) ? al : 0.f;
    }
    __syncthreads();
    if (t < 128){
        float a_ = 0.f;
        #pragma unroll 8
        for (int l = 0; l < 64; ++l) a_ += s_alpha[l]*s_seq[l][t];
        s_a[t] = a_;
    }
    __syncthreads();
    if (t < 128){
        int h = t;
        float o = bt[h];
        const float* wr = Wt + (size_t)h*256;
        #pragma unroll 8
        for (int k = 0; k < 128; ++k) o += s_a[k]*wr[k];
        #pragma unroll 8
        for (int k = 0; k < 128; ++k) o += s_ht[k]*wr[128+k];
        afin[(size_t)b*128 + h] = o;
    }
}

// ---------------- pred = 16 * afin @ emb[1:]^T ----------------
// block: 64 rows x 256 cols, 256 threads (8x8 per thread), grid (391, 8)
__global__ __launch_bounds__(256) void k_pred(
    const float* __restrict__ afin, const float* __restrict__ emb,
    float* __restrict__ outp)
{
    const int t = threadIdx.x;
    const int tc = t & 31;
    const int tg = t >> 5;
    const int cb = blockIdx.x * 256;
    const int rb = blockIdx.y * 64;

    __shared__ float s_a[64][132];
    __shared__ float s_e[256][33];

    #pragma unroll
    for (int c = 0; c < 8; ++c){
        int flat = c*1024 + t*4;
        int r = flat >> 7, k = flat & 127;
        *(float4*)&s_a[r][k] = *(const float4*)(afin + (size_t)(rb + r)*128 + k);
    }

    float acc[8][8];
    #pragma unroll
    for (int i = 0; i < 8; ++i)
        #pragma unroll
        for (int j = 0; j < 8; ++j) acc[i][j] = 0.f;

    for (int kc = 0; kc < 128; kc += 32){
        float4 ev[8];
        #pragma unroll
        for (int q = 0; q < 8; ++q){
            int f4 = q*256 + t;
            int row = f4 >> 3;
            int k4 = (f4 & 7) * 4;
            int v = cb + row;
            int srow = (v < 99999) ? (1 + v) : 0;
            ev[q] = *(const float4*)(emb + (size_t)srow*128 + kc + k4);
        }
        __syncthreads();
        #pragma unroll
        for (int q = 0; q < 8; ++q){
            int f4 = q*256 + t;
            int row = f4 >> 3;
            int k4 = (f4 & 7) * 4;
            s_e[row][k4+0] = ev[q].x;
            s_e[row][k4+1] = ev[q].y;
            s_e[row][k4+2] = ev[q].z;
            s_e[row][k4+3] = ev[q].w;
        }
        __syncthreads();
        #pragma unroll
        for (int k = 0; k < 32; ++k){
            float e_[8];
            #pragma unroll
            for (int q = 0; q < 8; ++q) e_[q] = s_e[tc + 32*q][k];
            #pragma unroll
            for (int i = 0; i < 8; ++i){
                float av = s_a[tg*8+i][kc+k];
                #pragma unroll
                for (int q = 0; q < 8; ++q) acc[i][q] += av*e_[q];
            }
        }
    }
    #pragma unroll
    for (int i = 0; i < 8; ++i){
        size_t rowoff = (size_t)(rb + tg*8 + i) * 99999;
        #pragma unroll
        for (int q = 0; q < 8; ++q){
            int v = cb + tc + 32*q;
            if (v < 99999) outp[rowoff + v] = 16.0f * acc[i][q];
        }
    }
}

extern "C" void kernel_launch(void* const* d_in, const int* in_sizes, int n_in,
                              void* d_out, int out_size, void* d_ws, size_t ws_size,
                              hipStream_t stream)
{
    const int*   items = (const int*)  d_in[0];
    const float* Amat  = (const float*)d_in[1];
    const int*   alias = (const int*)  d_in[2];
    const float* emb   = (const float*)d_in[3];
    const float* pos   = (const float*)d_in[4];
    const float* lp    = (const float*)d_in[5];
    const float* w_ih  = (const float*)d_in[6];
    const float* w_hh  = (const float*)d_in[7];
    const float* b_ih  = (const float*)d_in[8];
    const float* b_hh  = (const float*)d_in[9];
    const float* b_iah = (const float*)d_in[10];
    const float* b_oah = (const float*)d_in[11];
    const float* W_in  = (const float*)d_in[12];
    const float* b_in  = (const float*)d_in[13];
    const float* W_out = (const float*)d_in[14];
    const float* b_out = (const float*)d_in[15];
    const float* W1    = (const float*)d_in[16];
    const float* b1    = (const float*)d_in[17];
    const float* W2    = (const float*)d_in[18];
    const float* b2    = (const float*)d_in[19];
    const float* W3    = (const float*)d_in[20];
    const float* Wt    = (const float*)d_in[21];
    const float* bt    = (const float*)d_in[22];
    float* outp = (float*)d_out;

    float* wsf   = (float*)d_ws;
    float* w_ihT = wsf;             // 256*384 = 98304
    float* w_hhT = w_ihT + 98304;   // 128*384 = 49152
    float* W2T   = w_hhT + 49152;   // 128*128 = 16384
    float* htb   = W2T + 16384;     // 512*128 = 65536
    float* q1b   = htb + 65536;     // 65536
    float* afin  = q1b + 65536;     // 65536
    float* chunkbase = afin + 65536;

    // choose batch chunk so workspace fits
    int Bc = 512;
    while (Bc > 32){
        size_t need = ((size_t)360448 + (size_t)Bc*73728) * sizeof(float);
        if (need <= ws_size) break;
        Bc >>= 1;
    }
    const int M = Bc * 64;
    float* R0 = chunkbase;                  // hidden [M][128], later seq
    float* R1 = R0 + (size_t)M*128;         // inputs [M][256], later hidden_new [M][128]
    float* R2 = R1 + (size_t)M*256;         // gi [M][384], later q2 [M][128]
    float* R3 = R2 + (size_t)M*384;         // gh [M][384]

    ktrans<<<(384*256+255)/256, 256, 0, stream>>>(w_ih, w_ihT, 384, 256);
    ktrans<<<(384*128+255)/256, 256, 0, stream>>>(w_hh, w_hhT, 384, 128);
    ktrans<<<(128*128+255)/256, 256, 0, stream>>>(W2, W2T, 128, 128);

    for (int b0 = 0; b0 < 512; b0 += Bc){
        k_gnn_stage1<<<Bc, 256, 0, stream>>>(items, Amat, emb, W_in, b_in, W_out, b_out,
                                             b_iah, b_oah, R0, R1, b0);
        k_gemm<<<dim3(3, M/64), 256, 0, stream>>>(R1, w_ihT, b_ih, R2, M, 384, 256);
        k_gemm<<<dim3(3, M/64), 256, 0, stream>>>(R0, w_hhT, b_hh, R3, M, 384, 128);
        k_gate<<<M/8, 256, 0, stream>>>(R2, R3, R0, R1, M);
        k_seq<<<Bc, 256, 0, stream>>>(alias, pos, lp, R1, W1, b1, R0, htb, q1b, b0);
        k_gemm<<<dim3(1, M/64), 256, 0, stream>>>(R0, W2T, b2, R2, M, 128, 128);
        k_attn<<<Bc, 256, 0, stream>>>(alias, R0, R2, q1b, htb, W3, Wt, bt, afin, b0);
    }
    k_pred<<<dim3(391, 8), 256, 0, stream>>>(afin, emb, outp);
}

// Round 2
// 590.922 us; speedup vs baseline: 1.3353x; 1.3353x over previous
//
#include <hip/hip_runtime.h>
#include <cstddef>
#include <cstdint>

typedef __attribute__((ext_vector_type(8))) short short8v;
typedef __attribute__((ext_vector_type(4))) float f32x4;

__device__ __forceinline__ float sigmoidf_(float x){ return 1.0f/(1.0f + __expf(-x)); }

__device__ __forceinline__ void split_bf16(float x, unsigned short &hi, unsigned short &lo){
    union { float f; uint32_t u; } v; v.f = x;
    uint32_t r = v.u + 0x7FFFu + ((v.u >> 16) & 1u);
    hi = (unsigned short)(r >> 16);
    union { uint32_t u; float f; } hf; hf.u = ((uint32_t)hi) << 16;
    float res = x - hf.f;
    union { float f; uint32_t u; } w; w.f = res;
    uint32_t r2 = w.u + 0x7FFFu + ((w.u >> 16) & 1u);
    lo = (unsigned short)(r2 >> 16);
}

// ---------------- generic transpose (tiny weights only) ----------------
__global__ void ktrans(const float* __restrict__ src, float* __restrict__ dst, int R, int C)
{
    int idx = blockIdx.x*256 + threadIdx.x;
    if (idx < R*C){ int r = idx / C; int c = idx - r*C; dst[c*R + r] = src[idx]; }
}

// ---------------- stage 1 (per batch): gather emb, hv_in/out, bmm -> inputs ----------------
__global__ __launch_bounds__(256) void k_gnn_stage1(
    const int* __restrict__ items, const float* __restrict__ Amat,
    const float* __restrict__ emb,
    const float* __restrict__ W_in, const float* __restrict__ b_in,
    const float* __restrict__ W_out, const float* __restrict__ b_out,
    const float* __restrict__ b_iah, const float* __restrict__ b_oah,
    float* __restrict__ hidden, float* __restrict__ inputs, int b0)
{
    const int t = threadIdx.x;
    const int lane = t & 63;
    const int w = t >> 6;
    const int bl = blockIdx.x;
    const int b = b0 + bl;

    __shared__ float s_hid[64][132];
    __shared__ float s_A[64][132];
    __shared__ float s_hvT[256][65];
    __shared__ int s_items[64];

    if (t < 64) s_items[t] = items[b*64 + t];
    __syncthreads();

    const float* Ab = Amat + (size_t)b * 8192;
    #pragma unroll
    for (int c = 0; c < 8; ++c){
        int flat = c*1024 + t*4;
        int n = flat >> 7, h = flat & 127;
        float4 v = *(const float4*)(emb + (size_t)s_items[n]*128 + h);
        *(float4*)&s_hid[n][h] = v;
        *(float4*)(hidden + (size_t)(bl*64 + n)*128 + h) = v;
        *(float4*)&s_A[n][h] = *(const float4*)(Ab + flat);
    }
    __syncthreads();

    {
        const int n = lane;
        float hrow[128];
        #pragma unroll
        for (int k = 0; k < 128; ++k) hrow[k] = s_hid[n][k];
        const float* Wsel = (w < 2) ? (W_in + (size_t)(w*64)*128) : (W_out + (size_t)((w-2)*64)*128);
        const float* bsel = (w < 2) ? (b_in + w*64) : (b_out + (w-2)*64);
        for (int jj = 0; jj < 64; ++jj){
            const float* Wr = Wsel + (size_t)jj*128;
            float a0 = bsel[jj], a1 = 0.f, a2 = 0.f, a3 = 0.f;
            #pragma unroll
            for (int k = 0; k < 128; k += 4){
                float4 wv = *(const float4*)(Wr + k);
                a0 += hrow[k+0]*wv.x;
                a1 += hrow[k+1]*wv.y;
                a2 += hrow[k+2]*wv.z;
                a3 += hrow[k+3]*wv.w;
            }
            s_hvT[w*64 + jj][n] = (a0+a1)+(a2+a3);
        }
    }
    __syncthreads();

    {
        float acc0[16], acc1[16];
        #pragma unroll
        for (int ni = 0; ni < 16; ++ni){ acc0[ni] = b_iah[lane]; acc1[ni] = b_iah[64+lane]; }
        for (int m = 0; m < 64; ++m){
            float hv0 = s_hvT[lane][m];
            float hv1 = s_hvT[64+lane][m];
            #pragma unroll
            for (int ni = 0; ni < 16; ++ni){
                float av = s_A[w*16+ni][m];
                acc0[ni] += av*hv0;
                acc1[ni] += av*hv1;
            }
        }
        #pragma unroll
        for (int ni = 0; ni < 16; ++ni){
            size_t rr = (size_t)(bl*64 + w*16 + ni)*256;
            inputs[rr + lane]    = acc0[ni];
            inputs[rr + 64+lane] = acc1[ni];
        }
        #pragma unroll
        for (int ni = 0; ni < 16; ++ni){ acc0[ni] = b_oah[lane]; acc1[ni] = b_oah[64+lane]; }
        for (int m = 0; m < 64; ++m){
            float hv0 = s_hvT[128+lane][m];
            float hv1 = s_hvT[192+lane][m];
            #pragma unroll
            for (int ni = 0; ni < 16; ++ni){
                float av = s_A[w*16+ni][64+m];
                acc0[ni] += av*hv0;
                acc1[ni] += av*hv1;
            }
        }
        #pragma unroll
        for (int ni = 0; ni < 16; ++ni){
            size_t rr = (size_t)(bl*64 + w*16 + ni)*256;
            inputs[rr + 128+lane] = acc0[ni];
            inputs[rr + 192+lane] = acc1[ni];
        }
    }
}

// ---------------- generic GEMM: C[M][N] = A[M][K] @ Bt[K][N] + bias[N] ----------------
__global__ __launch_bounds__(256) void k_gemm(
    const float* __restrict__ A, const float* __restrict__ Bt,
    const float* __restrict__ bias, float* __restrict__ C,
    int M, int N, int K)
{
    const int t = threadIdx.x;
    const int tc = t & 31, tr = t >> 5;
    const int rb = blockIdx.y * 64;
    const int cb = blockIdx.x * 128;

    __shared__ float As[64][36];
    __shared__ float Ws[32][132];

    float acc[8][4];
    {
        float4 bv = *(const float4*)(bias + cb + tc*4);
        #pragma unroll
        for (int i = 0; i < 8; ++i){ acc[i][0]=bv.x; acc[i][1]=bv.y; acc[i][2]=bv.z; acc[i][3]=bv.w; }
    }

    for (int kc = 0; kc < K; kc += 32){
        int arow = t >> 2;
        int ak0  = (t & 3) * 8;
        const float* asrc = A + (size_t)(rb + arow)*K + kc + ak0;
        float4 av0 = *(const float4*)(asrc);
        float4 av1 = *(const float4*)(asrc + 4);
        int wk  = t >> 3;
        int wc0 = (t & 7) * 16;
        const float* wsrc = Bt + (size_t)(kc + wk)*N + cb + wc0;
        float4 wv0 = *(const float4*)(wsrc);
        float4 wv1 = *(const float4*)(wsrc + 4);
        float4 wv2 = *(const float4*)(wsrc + 8);
        float4 wv3 = *(const float4*)(wsrc + 12);
        __syncthreads();
        *(float4*)&As[arow][ak0]   = av0;
        *(float4*)&As[arow][ak0+4] = av1;
        *(float4*)&Ws[wk][wc0]     = wv0;
        *(float4*)&Ws[wk][wc0+4]   = wv1;
        *(float4*)&Ws[wk][wc0+8]   = wv2;
        *(float4*)&Ws[wk][wc0+12]  = wv3;
        __syncthreads();
        #pragma unroll
        for (int k = 0; k < 32; ++k){
            float4 wv = *(const float4*)&Ws[k][tc*4];
            #pragma unroll
            for (int i = 0; i < 8; ++i){
                float a_ = As[tr*8+i][k];
                acc[i][0] += a_*wv.x; acc[i][1] += a_*wv.y;
                acc[i][2] += a_*wv.z; acc[i][3] += a_*wv.w;
            }
        }
    }
    #pragma unroll
    for (int i = 0; i < 8; ++i){
        float4 o; o.x=acc[i][0]; o.y=acc[i][1]; o.z=acc[i][2]; o.w=acc[i][3];
        *(float4*)(C + (size_t)(rb + tr*8 + i)*N + cb + tc*4) = o;
    }
}

// ---------------- GRU gate fuse ----------------
__global__ __launch_bounds__(256) void k_gate(
    const float* __restrict__ gi, const float* __restrict__ gh,
    const float* __restrict__ hid, float* __restrict__ outp, int M)
{
    int q = blockIdx.x*256 + threadIdx.x;
    if (q >= M*32) return;
    int r = q >> 5, h4 = (q & 31) << 2;
    const float* gir = gi + (size_t)r*384;
    const float* ghr = gh + (size_t)r*384;
    float4 xr = *(const float4*)(gir + h4);
    float4 yr = *(const float4*)(ghr + h4);
    float4 xi = *(const float4*)(gir + 128 + h4);
    float4 yi = *(const float4*)(ghr + 128 + h4);
    float4 xn = *(const float4*)(gir + 256 + h4);
    float4 yn = *(const float4*)(ghr + 256 + h4);
    float4 hv = *(const float4*)(hid + (size_t)r*128 + h4);
    float4 o;
    {
        float rg, ig, ng;
        rg = sigmoidf_(xr.x+yr.x); ig = sigmoidf_(xi.x+yi.x); ng = tanhf(xn.x + rg*yn.x); o.x = ng + ig*(hv.x - ng);
        rg = sigmoidf_(xr.y+yr.y); ig = sigmoidf_(xi.y+yi.y); ng = tanhf(xn.y + rg*yn.y); o.y = ng + ig*(hv.y - ng);
        rg = sigmoidf_(xr.z+yr.z); ig = sigmoidf_(xi.z+yi.z); ng = tanhf(xn.z + rg*yn.z); o.z = ng + ig*(hv.z - ng);
        rg = sigmoidf_(xr.w+yr.w); ig = sigmoidf_(xi.w+yi.w); ng = tanhf(xn.w + rg*yn.w); o.w = ng + ig*(hv.w - ng);
    }
    *(float4*)(outp + (size_t)r*128 + h4) = o;
}

// ---------------- seq: gather + [pos|seq]@linear_pos + tanh + l2norm; also ht & q1 ----------------
__global__ __launch_bounds__(256) void k_seq(
    const int* __restrict__ alias, const float* __restrict__ pos,
    const float* __restrict__ lp, const float* __restrict__ hn,
    const float* __restrict__ W1, const float* __restrict__ b1,
    float* __restrict__ seq, float* __restrict__ ht, float* __restrict__ q1,
    int b0)
{
    const int t = threadIdx.x;
    const int bl = blockIdx.x, b = b0 + bl;
    __shared__ float Xs[64][260];
    __shared__ float Ys[64][132];
    __shared__ int s_alias[64];
    __shared__ float s_rn[64];
    __shared__ int s_last;

    if (t < 64) s_alias[t] = alias[b*64 + t];
    __syncthreads();
    if (t == 0){
        int cnt = 0;
        for (int l = 0; l < 64; ++l) cnt += (s_alias[l] > 0) ? 1 : 0;
        s_last = (cnt - 1) & 63;
    }
    #pragma unroll
    for (int c = 0; c < 8; ++c){
        int flat = c*1024 + t*4;
        int l = flat >> 7, k = flat & 127;
        *(float4*)&Xs[l][k] = *(const float4*)(pos + l*128 + k);
        int row = s_alias[l];
        *(float4*)&Xs[l][128+k] = *(const float4*)(hn + (size_t)(bl*64 + row)*128 + k);
    }
    __syncthreads();

    const int tc = t & 31, tr = t >> 5;
    float acc[8][4];
    #pragma unroll
    for (int i=0;i<8;i++){ acc[i][0]=0.f; acc[i][1]=0.f; acc[i][2]=0.f; acc[i][3]=0.f; }

    for (int k = 0; k < 256; k += 4){
        float4 w0 = *(const float4*)(lp + (size_t)(k+0)*128 + tc*4);
        float4 w1 = *(const float4*)(lp + (size_t)(k+1)*128 + tc*4);
        float4 w2 = *(const float4*)(lp + (size_t)(k+2)*128 + tc*4);
        float4 w3 = *(const float4*)(lp + (size_t)(k+3)*128 + tc*4);
        #pragma unroll
        for (int i = 0; i < 8; ++i){
            float4 a4 = *(const float4*)&Xs[tr*8+i][k];
            acc[i][0] += a4.x*w0.x + a4.y*w1.x + a4.z*w2.x + a4.w*w3.x;
            acc[i][1] += a4.x*w0.y + a4.y*w1.y + a4.z*w2.y + a4.w*w3.y;
            acc[i][2] += a4.x*w0.z + a4.y*w1.z + a4.z*w2.z + a4.w*w3.z;
            acc[i][3] += a4.x*w0.w + a4.y*w1.w + a4.z*w2.w + a4.w*w3.w;
        }
    }
    #pragma unroll
    for (int i = 0; i < 8; ++i){
        float4 o;
        o.x = tanhf(acc[i][0]); o.y = tanhf(acc[i][1]);
        o.z = tanhf(acc[i][2]); o.w = tanhf(acc[i][3]);
        *(float4*)&Ys[tr*8+i][tc*4] = o;
    }
    __syncthreads();
    if (t < 64){
        float s = 0.f;
        #pragma unroll 8
        for (int k = 0; k < 128; ++k){ float v = Ys[t][k]; s = fmaf(v, v, s); }
        s_rn[t] = rsqrtf(s);
    }
    __syncthreads();
    #pragma unroll
    for (int c = 0; c < 8; ++c){
        int flat = c*1024 + t*4;
        int l = flat >> 7, k = flat & 127;
        float rn = s_rn[l];
        float4 o;
        o.x = Ys[l][k+0]*rn; o.y = Ys[l][k+1]*rn; o.z = Ys[l][k+2]*rn; o.w = Ys[l][k+3]*rn;
        *(float4*)(seq + (size_t)(bl*64 + l)*128 + k) = o;
    }
    if (t < 128){
        int h = t;
        int lst = s_last;
        float rn = s_rn[lst];
        float hv = Ys[lst][h]*rn;
        ht[(size_t)b*128 + h] = hv;
        float o = b1[h];
        const float* wr = W1 + (size_t)h*128;
        #pragma unroll 8
        for (int k = 0; k < 128; ++k) o += (Ys[lst][k]*rn) * wr[k];
        q1[(size_t)b*128 + h] = o;
    }
}

// ---------------- attention + final projection a_final ----------------
__global__ __launch_bounds__(256) void k_attn(
    const int* __restrict__ alias, const float* __restrict__ seq,
    const float* __restrict__ q2m, const float* __restrict__ q1,
    const float* __restrict__ ht, const float* __restrict__ W3,
    const float* __restrict__ Wt, const float* __restrict__ bt,
    float* __restrict__ afin, int b0)
{
    const int t = threadIdx.x;
    const int bl = blockIdx.x, b = b0 + bl;
    __shared__ float s_seq[64][132];
    __shared__ float s_q2[64][132];
    __shared__ float s_q1[128], s_ht[128];
    __shared__ float s_part[64][4];
    __shared__ float s_alpha[64];
    __shared__ float s_a[128];
    __shared__ int s_alias2[64];

    if (t < 64) s_alias2[t] = alias[b*64 + t];
    if (t < 128){ s_q1[t] = q1[(size_t)b*128 + t]; s_ht[t] = ht[(size_t)b*128 + t]; }
    #pragma unroll
    for (int c = 0; c < 8; ++c){
        int flat = c*1024 + t*4;
        int l = flat >> 7, k = flat & 127;
        *(float4*)&s_seq[l][k] = *(const float4*)(seq + (size_t)(bl*64 + l)*128 + k);
        *(float4*)&s_q2[l][k]  = *(const float4*)(q2m + (size_t)(bl*64 + l)*128 + k);
    }
    __syncthreads();
    {
        int l = t >> 2, g = t & 3;
        float p = 0.f;
        #pragma unroll 8
        for (int hh = 0; hh < 32; ++hh){
            int h = g*32 + hh;
            float sv = sigmoidf_(s_q1[h] + s_q2[l][h]);
            p += sv * W3[h];
        }
        s_part[l][g] = p;
    }
    __syncthreads();
    if (t < 64){
        float al = s_part[t][0] + s_part[t][1] + s_part[t][2] + s_part[t][3];
        s_alpha[t] = (s_alias2[t] > 0) ? al : 0.f;
    }
    __syncthreads();
    if (t < 128){
        float a_ = 0.f;
        #pragma unroll 8
        for (int l = 0; l < 64; ++l) a_ += s_alpha[l]*s_seq[l][t];
        s_a[t] = a_;
    }
    __syncthreads();
    if (t < 128){
        int h = t;
        float o = bt[h];
        const float* wr = Wt + (size_t)h*256;
        #pragma unroll 8
        for (int k = 0; k < 128; ++k) o += s_a[k]*wr[k];
        #pragma unroll 8
        for (int k = 0; k < 128; ++k) o += s_ht[k]*wr[128+k];
        afin[(size_t)b*128 + h] = o;
    }
}

// ---------------- prep: afin f32 -> bf16 hi/lo fragments ----------------
// Layout: [mt(32)][ks(4)][lane(64)][e(8)]; row = mt*16+(lane&15), k = ks*32+(lane>>4)*8+e
__global__ __launch_bounds__(256) void k_prep_pred(
    const float* __restrict__ afin, unsigned short* __restrict__ Ahi,
    unsigned short* __restrict__ Alo)
{
    int idx = blockIdx.x*256 + threadIdx.x;      // 0..8191
    int lane = idx & 63;
    int tile = idx >> 6;                          // mt*4+ks
    int mt = tile >> 2, ks = tile & 3;
    int row = mt*16 + (lane & 15);
    int k0  = ks*32 + (lane >> 4)*8;
    const float* src = afin + (size_t)row*128 + k0;
    float4 f0 = *(const float4*)(src);
    float4 f1 = *(const float4*)(src + 4);
    float xs[8] = {f0.x,f0.y,f0.z,f0.w,f1.x,f1.y,f1.z,f1.w};
    unsigned short hi[8], lo[8];
    #pragma unroll
    for (int e = 0; e < 8; ++e) split_bf16(xs[e], hi[e], lo[e]);
    unsigned short* dh = Ahi + (size_t)idx*8;
    unsigned short* dl = Alo + (size_t)idx*8;
    #pragma unroll
    for (int e = 0; e < 8; ++e){ dh[e] = hi[e]; dl[e] = lo[e]; }
}

// ---------------- pred = 16 * afin @ emb[1:]^T  via MFMA bf16 split ----------------
// grid: 1563 blocks, each 64 vocab cols x all 512 rows. 256 threads = 4 waves.
#define NVOCAB 99999
__global__ __launch_bounds__(256) void k_pred_mfma(
    const unsigned short* __restrict__ Ahi, const unsigned short* __restrict__ Alo,
    const float* __restrict__ emb, float* __restrict__ outp)
{
    const int t = threadIdx.x;
    const int lane = t & 63;
    const int w = t >> 6;
    const int cb = blockIdx.x * 64;

    __shared__ float s_e[64][132];

    // load 64 emb rows (vocab ids cb..cb+63 -> emb rows +1) of 128 f32
    #pragma unroll
    for (int c = 0; c < 8; ++c){
        int flat4 = c*256 + t;            // 0..2047
        int row = flat4 >> 5;
        int k4  = (flat4 & 31) * 4;
        int v = cb + row;
        int srow = (v < NVOCAB) ? (v + 1) : 0;
        *(float4*)&s_e[row][k4] = *(const float4*)(emb + (size_t)srow*128 + k4);
    }
    __syncthreads();

    // build B fragments (same in all 4 waves): B[k][col], col=nt*16+(lane&15), k=ks*32+(lane>>4)*8+e
    short8v bhi[4][4], blo[4][4];
    {
        const int col = lane & 15;
        const int kg  = (lane >> 4) * 8;
        #pragma unroll
        for (int nt = 0; nt < 4; ++nt){
            #pragma unroll
            for (int ks = 0; ks < 4; ++ks){
                const float* p = &s_e[nt*16 + col][ks*32 + kg];
                float4 f0 = *(const float4*)(p);
                float4 f1 = *(const float4*)(p + 4);
                float xs[8] = {f0.x,f0.y,f0.z,f0.w,f1.x,f1.y,f1.z,f1.w};
                short8v h, l;
                #pragma unroll
                for (int e = 0; e < 8; ++e){
                    unsigned short uh, ul;
                    split_bf16(xs[e], uh, ul);
                    h[e] = (short)uh; l[e] = (short)ul;
                }
                bhi[nt][ks] = h; blo[nt][ks] = l;
            }
        }
    }

    // m-tiles: wave w handles mt = w, w+4, ..., w+28
    for (int mt = w; mt < 32; mt += 4){
        short8v ahi[4], alo[4];
        #pragma unroll
        for (int ks = 0; ks < 4; ++ks){
            size_t off = ((size_t)(mt*4 + ks)*64 + lane)*8;
            ahi[ks] = *(const short8v*)(Ahi + off);
            alo[ks] = *(const short8v*)(Alo + off);
        }
        const int r0 = mt*16 + (lane >> 4)*4;
        const int colrel = lane & 15;
        #pragma unroll
        for (int nt = 0; nt < 4; ++nt){
            f32x4 acc = {0.f, 0.f, 0.f, 0.f};
            #pragma unroll
            for (int ks = 0; ks < 4; ++ks){
                acc = __builtin_amdgcn_mfma_f32_16x16x32_bf16(ahi[ks], bhi[nt][ks], acc, 0, 0, 0);
                acc = __builtin_amdgcn_mfma_f32_16x16x32_bf16(alo[ks], bhi[nt][ks], acc, 0, 0, 0);
                acc = __builtin_amdgcn_mfma_f32_16x16x32_bf16(ahi[ks], blo[nt][ks], acc, 0, 0, 0);
            }
            int col = cb + nt*16 + colrel;
            if (col < NVOCAB){
                #pragma unroll
                for (int j = 0; j < 4; ++j)
                    outp[(size_t)(r0 + j)*NVOCAB + col] = 16.0f * acc[j];
            }
        }
    }
}

extern "C" void kernel_launch(void* const* d_in, const int* in_sizes, int n_in,
                              void* d_out, int out_size, void* d_ws, size_t ws_size,
                              hipStream_t stream)
{
    const int*   items = (const int*)  d_in[0];
    const float* Amat  = (const float*)d_in[1];
    const int*   alias = (const int*)  d_in[2];
    const float* emb   = (const float*)d_in[3];
    const float* pos   = (const float*)d_in[4];
    const float* lp    = (const float*)d_in[5];
    const float* w_ih  = (const float*)d_in[6];
    const float* w_hh  = (const float*)d_in[7];
    const float* b_ih  = (const float*)d_in[8];
    const float* b_hh  = (const float*)d_in[9];
    const float* b_iah = (const float*)d_in[10];
    const float* b_oah = (const float*)d_in[11];
    const float* W_in  = (const float*)d_in[12];
    const float* b_in  = (const float*)d_in[13];
    const float* W_out = (const float*)d_in[14];
    const float* b_out = (const float*)d_in[15];
    const float* W1    = (const float*)d_in[16];
    const float* b1    = (const float*)d_in[17];
    const float* W2    = (const float*)d_in[18];
    const float* b2    = (const float*)d_in[19];
    const float* W3    = (const float*)d_in[20];
    const float* Wt    = (const float*)d_in[21];
    const float* bt    = (const float*)d_in[22];
    float* outp = (float*)d_out;

    float* wsf   = (float*)d_ws;
    float* w_ihT = wsf;             // 256*384 = 98304
    float* w_hhT = w_ihT + 98304;   // 128*384 = 49152
    float* W2T   = w_hhT + 49152;   // 128*128 = 16384
    float* htb   = W2T + 16384;     // 512*128 = 65536
    float* q1b   = htb + 65536;     // 65536
    float* afin  = q1b + 65536;     // 65536
    unsigned short* Ahi = (unsigned short*)(afin + 65536);  // 65536 ushort
    unsigned short* Alo = Ahi + 65536;                      // 65536 ushort
    float* chunkbase = afin + 65536 + 65536;                // Ahi+Alo = 65536 floats

    int Bc = 512;
    while (Bc > 32){
        size_t need = ((size_t)425984 + (size_t)Bc*73728) * sizeof(float);
        if (need <= ws_size) break;
        Bc >>= 1;
    }
    const int M = Bc * 64;
    float* R0 = chunkbase;                  // hidden [M][128], later seq
    float* R1 = R0 + (size_t)M*128;         // inputs [M][256], later hidden_new [M][128]
    float* R2 = R1 + (size_t)M*256;         // gi [M][384], later q2 [M][128]
    float* R3 = R2 + (size_t)M*384;         // gh [M][384]

    ktrans<<<(384*256+255)/256, 256, 0, stream>>>(w_ih, w_ihT, 384, 256);
    ktrans<<<(384*128+255)/256, 256, 0, stream>>>(w_hh, w_hhT, 384, 128);
    ktrans<<<(128*128+255)/256, 256, 0, stream>>>(W2, W2T, 128, 128);

    for (int b0 = 0; b0 < 512; b0 += Bc){
        k_gnn_stage1<<<Bc, 256, 0, stream>>>(items, Amat, emb, W_in, b_in, W_out, b_out,
                                             b_iah, b_oah, R0, R1, b0);
        k_gemm<<<dim3(3, M/64), 256, 0, stream>>>(R1, w_ihT, b_ih, R2, M, 384, 256);
        k_gemm<<<dim3(3, M/64), 256, 0, stream>>>(R0, w_hhT, b_hh, R3, M, 384, 128);
        k_gate<<<M/8, 256, 0, stream>>>(R2, R3, R0, R1, M);
        k_seq<<<Bc, 256, 0, stream>>>(alias, pos, lp, R1, W1, b1, R0, htb, q1b, b0);
        k_gemm<<<dim3(1, M/64), 256, 0, stream>>>(R0, W2T, b2, R2, M, 128, 128);
        k_attn<<<Bc, 256, 0, stream>>>(alias, R0, R2, q1b, htb, W3, Wt, bt, afin, b0);
    }
    k_prep_pred<<<32, 256, 0, stream>>>(afin, Ahi, Alo);
    k_pred_mfma<<<(NVOCAB + 63)/64, 256, 0, stream>>>(Ahi, Alo, emb, outp);
}

// Round 3
// 508.450 us; speedup vs baseline: 1.5519x; 1.1622x over previous
//
#include <hip/hip_runtime.h>
#include <cstddef>
#include <cstdint>

typedef __attribute__((ext_vector_type(8))) short short8v;
typedef __attribute__((ext_vector_type(4))) short short4v;
typedef __attribute__((ext_vector_type(4))) float f32x4;

__device__ __forceinline__ float sigmoidf_(float x){ return 1.0f/(1.0f + __expf(-x)); }

__device__ __forceinline__ void split_bf16(float x, unsigned short &hi, unsigned short &lo){
    union { float f; uint32_t u; } v; v.f = x;
    uint32_t r = v.u + 0x7FFFu + ((v.u >> 16) & 1u);
    hi = (unsigned short)(r >> 16);
    union { uint32_t u; float f; } hf; hf.u = ((uint32_t)hi) << 16;
    float res = x - hf.f;
    union { float f; uint32_t u; } w; w.f = res;
    uint32_t r2 = w.u + 0x7FFFu + ((w.u >> 16) & 1u);
    lo = (unsigned short)(r2 >> 16);
}

__device__ __forceinline__ void split8(const float* xs, short8v &h, short8v &l){
    #pragma unroll
    for (int e = 0; e < 8; ++e){
        unsigned short uh, ul;
        split_bf16(xs[e], uh, ul);
        h[e] = (short)uh; l[e] = (short)ul;
    }
}

// ---------------- generic transpose (tiny weights only) ----------------
__global__ void ktrans(const float* __restrict__ src, float* __restrict__ dst, int R, int C)
{
    int idx = blockIdx.x*256 + threadIdx.x;
    if (idx < R*C){ int r = idx / C; int c = idx - r*C; dst[c*R + r] = src[idx]; }
}

// ---------------- prep: split weights into B-fragment layout ----------------
// frag index: ((nt*KS + ks)*64 + lane)*8 + e ; value = W^T[k][col], col=nt*16+(lane&15), k=ks*32+(lane>>4)*8+e
__global__ __launch_bounds__(256) void k_prep_wfrag(
    const float* __restrict__ W_in, const float* __restrict__ W_out,
    const float* __restrict__ w_ih, const float* __restrict__ w_hh,
    unsigned short* __restrict__ wo_hi, unsigned short* __restrict__ wo_lo,
    unsigned short* __restrict__ wih_hi, unsigned short* __restrict__ wih_lo,
    unsigned short* __restrict__ whh_hi, unsigned short* __restrict__ whh_lo)
{
    int id = blockIdx.x*256 + threadIdx.x;
    const float* src; unsigned short *dh, *dl;
    if (id < 4096){
        int lane=id&63, tile=id>>6, nt=tile>>2, ks=tile&3;
        int col=nt*16+(lane&15), k=ks*32+(lane>>4)*8;
        src = (col<128) ? (W_in + (size_t)col*128 + k) : (W_out + (size_t)(col-128)*128 + k);
        dh=wo_hi+(size_t)id*8; dl=wo_lo+(size_t)id*8;
    } else if (id < 16384){
        int t2=id-4096, lane=t2&63, tile=t2>>6, nt=tile>>3, ks=tile&7;
        int col=nt*16+(lane&15), k=ks*32+(lane>>4)*8;
        src = w_ih + (size_t)col*256 + k;
        dh=wih_hi+(size_t)t2*8; dl=wih_lo+(size_t)t2*8;
    } else if (id < 22528){
        int t3=id-16384, lane=t3&63, tile=t3>>6, nt=tile>>2, ks=tile&3;
        int col=nt*16+(lane&15), k=ks*32+(lane>>4)*8;
        src = w_hh + (size_t)col*128 + k;
        dh=whh_hi+(size_t)t3*8; dl=whh_lo+(size_t)t3*8;
    } else return;
    float4 f0=*(const float4*)src, f1=*(const float4*)(src+4);
    float xs[8]={f0.x,f0.y,f0.z,f0.w,f1.x,f1.y,f1.z,f1.w};
    short8v h,l; split8(xs,h,l);
    *(short8v*)dh = h; *(short8v*)dl = l;
}

// ---------------- K1: gather + hv GEMM + bmm, emit hidden f32 + A-frag splits ----------------
union SharedU {
    struct { unsigned short hi[256][72]; unsigned short lo[256][72]; } hvT;  // 73728 B
    float inp[64][268];                                                      // 68608 B
};

__global__ __launch_bounds__(256) void k_gnn1(
    const int* __restrict__ items, const float* __restrict__ Amat,
    const float* __restrict__ emb,
    const float* __restrict__ b_in, const float* __restrict__ b_out,
    const float* __restrict__ b_iah, const float* __restrict__ b_oah,
    const unsigned short* __restrict__ wo_hi, const unsigned short* __restrict__ wo_lo,
    float* __restrict__ hidden,
    unsigned short* __restrict__ hid_hi, unsigned short* __restrict__ hid_lo,
    unsigned short* __restrict__ inp_hi, unsigned short* __restrict__ inp_lo)
{
    const int t=threadIdx.x, lane=t&63, w=t>>6, bl=blockIdx.x;
    const int c15=lane&15, g=lane>>4, kg=g*8;
    const int mt=w;
    const int row=mt*16+c15;

    __shared__ int s_items[64];
    __shared__ SharedU U;

    if (t < 64) s_items[t]=items[bl*64+t];
    __syncthreads();

    // gather + split hidden (A-frag in regs) + store f32 + frag global
    short8v hhi[4], hlo[4];
    {
        const float* src = emb + (size_t)s_items[row]*128;
        float* hd = hidden + (size_t)(bl*64+row)*128;
        #pragma unroll
        for (int ks=0; ks<4; ++ks){
            float4 f0=*(const float4*)(src+ks*32+kg);
            float4 f1=*(const float4*)(src+ks*32+kg+4);
            *(float4*)(hd+ks*32+kg)=f0; *(float4*)(hd+ks*32+kg+4)=f1;
            float xs[8]={f0.x,f0.y,f0.z,f0.w,f1.x,f1.y,f1.z,f1.w};
            short8v h,l; split8(xs,h,l);
            hhi[ks]=h; hlo[ks]=l;
            size_t off=((size_t)(bl*4+mt)*4+ks)*512 + lane*8;
            *(short8v*)(hid_hi+off)=h; *(short8v*)(hid_lo+off)=l;
        }
    }

    // hv GEMM: hv[64][256] = hidden @ [W_in^T|W_out^T] + bias
    f32x4 acc[16];
    #pragma unroll
    for (int nt=0;nt<16;++nt){
        int col=nt*16+c15;
        float bv=(col<128)? b_in[col] : b_out[col-128];
        acc[nt]=(f32x4){bv,bv,bv,bv};
    }
    for (int ks=0; ks<4; ++ks){
        #pragma unroll
        for (int nt=0; nt<16; ++nt){
            size_t wo=((size_t)(nt*4+ks)*64+lane)*8;
            short8v bh=*(const short8v*)(wo_hi+wo);
            short8v bl_=*(const short8v*)(wo_lo+wo);
            acc[nt]=__builtin_amdgcn_mfma_f32_16x16x32_bf16(hhi[ks],bh,acc[nt],0,0,0);
            acc[nt]=__builtin_amdgcn_mfma_f32_16x16x32_bf16(hlo[ks],bh,acc[nt],0,0,0);
            acc[nt]=__builtin_amdgcn_mfma_f32_16x16x32_bf16(hhi[ks],bl_,acc[nt],0,0,0);
        }
    }

    // write hv transposed bf16 to LDS: hvT[col][m-row]
    {
        const int r0=g*4;
        #pragma unroll
        for (int nt=0;nt<16;++nt){
            int col=nt*16+c15;
            short4v h4,l4;
            #pragma unroll
            for (int j=0;j<4;++j){
                unsigned short uh,ul; split_bf16(acc[nt][j],uh,ul);
                h4[j]=(short)uh; l4[j]=(short)ul;
            }
            *(short4v*)&U.hvT.hi[col][mt*16+r0] = h4;
            *(short4v*)&U.hvT.lo[col][mt*16+r0] = l4;
        }
    }
    __syncthreads();

    // bmm: inputs[n][0:128] = A_in @ hv[:, :128] + b_iah ; [128:256] = A_out @ hv[:,128:] + b_oah
    f32x4 acc2[16];
    #pragma unroll
    for (int nt=0;nt<16;++nt){
        int col=nt*16+c15;
        float bv=(col<128)? b_iah[col] : b_oah[col-128];
        acc2[nt]=(f32x4){bv,bv,bv,bv};
    }
    short8v aihi[2],ailo[2],aohi[2],aolo[2];
    {
        const float* Ab = Amat + (size_t)bl*8192 + (size_t)row*128;
        #pragma unroll
        for (int ks=0;ks<2;++ks){
            float4 f0=*(const float4*)(Ab+ks*32+kg);
            float4 f1=*(const float4*)(Ab+ks*32+kg+4);
            float xs[8]={f0.x,f0.y,f0.z,f0.w,f1.x,f1.y,f1.z,f1.w};
            split8(xs,aihi[ks],ailo[ks]);
            float4 g0=*(const float4*)(Ab+64+ks*32+kg);
            float4 g1=*(const float4*)(Ab+64+ks*32+kg+4);
            float ys[8]={g0.x,g0.y,g0.z,g0.w,g1.x,g1.y,g1.z,g1.w};
            split8(ys,aohi[ks],aolo[ks]);
        }
    }
    for (int ks=0;ks<2;++ks){
        #pragma unroll
        for (int nt=0;nt<16;++nt){
            int h=nt*16+c15;
            int m0=ks*32+kg;
            short8v bh=*(const short8v*)&U.hvT.hi[h][m0];
            short8v bl_=*(const short8v*)&U.hvT.lo[h][m0];
            short8v ah=(nt<8)?aihi[ks]:aohi[ks];
            short8v al=(nt<8)?ailo[ks]:aolo[ks];
            acc2[nt]=__builtin_amdgcn_mfma_f32_16x16x32_bf16(ah,bh,acc2[nt],0,0,0);
            acc2[nt]=__builtin_amdgcn_mfma_f32_16x16x32_bf16(al,bh,acc2[nt],0,0,0);
            acc2[nt]=__builtin_amdgcn_mfma_f32_16x16x32_bf16(ah,bl_,acc2[nt],0,0,0);
        }
    }
    __syncthreads();   // done reading hvT

    // write inputs f32 to LDS row-major (transpose C-layout -> row layout)
    {
        #pragma unroll
        for (int nt=0;nt<16;++nt){
            int col=nt*16+c15;
            #pragma unroll
            for (int j=0;j<4;++j)
                U.inp[mt*16+g*4+j][col]=acc2[nt][j];
        }
    }
    __syncthreads();

    // read A-frags of inputs, split, store global
    {
        #pragma unroll
        for (int ks=0;ks<8;++ks){
            float4 f0=*(const float4*)&U.inp[row][ks*32+kg];
            float4 f1=*(const float4*)&U.inp[row][ks*32+kg+4];
            float xs[8]={f0.x,f0.y,f0.z,f0.w,f1.x,f1.y,f1.z,f1.w};
            short8v h,l; split8(xs,h,l);
            size_t off=((size_t)(bl*4+mt)*8+ks)*512 + lane*8;
            *(short8v*)(inp_hi+off)=h; *(short8v*)(inp_lo+off)=l;
        }
    }
}

// ---------------- K2: gi/gh GEMMs + GRU gate, LDS-staged weights ----------------
__global__ __launch_bounds__(512) void k_gru(
    const unsigned short* __restrict__ inp_hi, const unsigned short* __restrict__ inp_lo,
    const unsigned short* __restrict__ hid_hi, const unsigned short* __restrict__ hid_lo,
    const unsigned short* __restrict__ wih_hi, const unsigned short* __restrict__ wih_lo,
    const unsigned short* __restrict__ whh_hi, const unsigned short* __restrict__ whh_lo,
    const float* __restrict__ b_ih, const float* __restrict__ b_hh,
    const float* __restrict__ hidden, float* __restrict__ hidnew)
{
    const int t=threadIdx.x, lane=t&63, w=t>>6;
    const int gmt = blockIdx.x*8 + w;
    const int c15=lane&15, g=lane>>4;

    __shared__ unsigned short wbuf[2][24][1024];

    auto stage=[&](int ks, int buf){
        #pragma unroll
        for (int i=0;i<3;++i){
            int idx=i*512+t;
            int nt=idx>>6, ln=idx&63;
            const unsigned short *sh, *sl;
            if (ks<4){ size_t o=((size_t)(nt*4+ks)*64+ln)*8; sh=whh_hi+o; sl=whh_lo+o; }
            else     { size_t o=((size_t)(nt*8+(ks-4))*64+ln)*8; sh=wih_hi+o; sl=wih_lo+o; }
            *(short8v*)&wbuf[buf][nt][ln*8]     = *(const short8v*)sh;
            *(short8v*)&wbuf[buf][nt][512+ln*8] = *(const short8v*)sl;
        }
    };

    f32x4 agi[24], agh[24];
    #pragma unroll
    for (int nt=0;nt<24;++nt){
        int col=nt*16+c15;
        float bi=b_ih[col], bh=b_hh[col];
        agi[nt]=(f32x4){bi,bi,bi,bi};
        agh[nt]=(f32x4){bh,bh,bh,bh};
    }

    stage(0,0);
    __syncthreads();
    for (int ks=0; ks<12; ++ks){
        int buf=ks&1;
        if (ks<11) stage(ks+1, buf^1);
        short8v ah, al;
        if (ks<4){
            size_t o=((size_t)gmt*4+ks)*512 + (size_t)lane*8;
            ah=*(const short8v*)(hid_hi+o); al=*(const short8v*)(hid_lo+o);
        } else {
            size_t o=((size_t)gmt*8+(ks-4))*512 + (size_t)lane*8;
            ah=*(const short8v*)(inp_hi+o); al=*(const short8v*)(inp_lo+o);
        }
        if (ks<4){
            #pragma unroll
            for (int nt=0;nt<24;++nt){
                short8v bh=*(const short8v*)&wbuf[buf][nt][lane*8];
                short8v bl_=*(const short8v*)&wbuf[buf][nt][512+lane*8];
                agh[nt]=__builtin_amdgcn_mfma_f32_16x16x32_bf16(ah,bh,agh[nt],0,0,0);
                agh[nt]=__builtin_amdgcn_mfma_f32_16x16x32_bf16(al,bh,agh[nt],0,0,0);
                agh[nt]=__builtin_amdgcn_mfma_f32_16x16x32_bf16(ah,bl_,agh[nt],0,0,0);
            }
        } else {
            #pragma unroll
            for (int nt=0;nt<24;++nt){
                short8v bh=*(const short8v*)&wbuf[buf][nt][lane*8];
                short8v bl_=*(const short8v*)&wbuf[buf][nt][512+lane*8];
                agi[nt]=__builtin_amdgcn_mfma_f32_16x16x32_bf16(ah,bh,agi[nt],0,0,0);
                agi[nt]=__builtin_amdgcn_mfma_f32_16x16x32_bf16(al,bh,agi[nt],0,0,0);
                agi[nt]=__builtin_amdgcn_mfma_f32_16x16x32_bf16(ah,bl_,agi[nt],0,0,0);
            }
        }
        __syncthreads();
    }

    // fused GRU gate
    const int r0=gmt*16+g*4;
    #pragma unroll
    for (int nt=0;nt<8;++nt){
        int h=nt*16+c15;
        #pragma unroll
        for (int j=0;j<4;++j){
            float ir=agi[nt][j], ii=agi[nt+8][j], in_=agi[nt+16][j];
            float hr=agh[nt][j], hi_=agh[nt+8][j], hn=agh[nt+16][j];
            float rg=sigmoidf_(ir+hr), ig=sigmoidf_(ii+hi_);
            float ng=tanhf(in_+rg*hn);
            float ho=hidden[(size_t)(r0+j)*128+h];
            hidnew[(size_t)(r0+j)*128+h]=ng+ig*(ho-ng);
        }
    }
}

// ---------------- generic fp32 GEMM (kept for q2) ----------------
__global__ __launch_bounds__(256) void k_gemm(
    const float* __restrict__ A, const float* __restrict__ Bt,
    const float* __restrict__ bias, float* __restrict__ C,
    int M, int N, int K)
{
    const int t = threadIdx.x;
    const int tc = t & 31, tr = t >> 5;
    const int rb = blockIdx.y * 64;
    const int cb = blockIdx.x * 128;

    __shared__ float As[64][36];
    __shared__ float Ws[32][132];

    float acc[8][4];
    {
        float4 bv = *(const float4*)(bias + cb + tc*4);
        #pragma unroll
        for (int i = 0; i < 8; ++i){ acc[i][0]=bv.x; acc[i][1]=bv.y; acc[i][2]=bv.z; acc[i][3]=bv.w; }
    }

    for (int kc = 0; kc < K; kc += 32){
        int arow = t >> 2;
        int ak0  = (t & 3) * 8;
        const float* asrc = A + (size_t)(rb + arow)*K + kc + ak0;
        float4 av0 = *(const float4*)(asrc);
        float4 av1 = *(const float4*)(asrc + 4);
        int wk  = t >> 3;
        int wc0 = (t & 7) * 16;
        const float* wsrc = Bt + (size_t)(kc + wk)*N + cb + wc0;
        float4 wv0 = *(const float4*)(wsrc);
        float4 wv1 = *(const float4*)(wsrc + 4);
        float4 wv2 = *(const float4*)(wsrc + 8);
        float4 wv3 = *(const float4*)(wsrc + 12);
        __syncthreads();
        *(float4*)&As[arow][ak0]   = av0;
        *(float4*)&As[arow][ak0+4] = av1;
        *(float4*)&Ws[wk][wc0]     = wv0;
        *(float4*)&Ws[wk][wc0+4]   = wv1;
        *(float4*)&Ws[wk][wc0+8]   = wv2;
        *(float4*)&Ws[wk][wc0+12]  = wv3;
        __syncthreads();
        #pragma unroll
        for (int k = 0; k < 32; ++k){
            float4 wv = *(const float4*)&Ws[k][tc*4];
            #pragma unroll
            for (int i = 0; i < 8; ++i){
                float a_ = As[tr*8+i][k];
                acc[i][0] += a_*wv.x; acc[i][1] += a_*wv.y;
                acc[i][2] += a_*wv.z; acc[i][3] += a_*wv.w;
            }
        }
    }
    #pragma unroll
    for (int i = 0; i < 8; ++i){
        float4 o; o.x=acc[i][0]; o.y=acc[i][1]; o.z=acc[i][2]; o.w=acc[i][3];
        *(float4*)(C + (size_t)(rb + tr*8 + i)*N + cb + tc*4) = o;
    }
}

// ---------------- seq: gather + [pos|seq]@linear_pos + tanh + l2norm; also ht & q1 ----------------
__global__ __launch_bounds__(256) void k_seq(
    const int* __restrict__ alias, const float* __restrict__ pos,
    const float* __restrict__ lp, const float* __restrict__ hn,
    const float* __restrict__ W1, const float* __restrict__ b1,
    float* __restrict__ seq, float* __restrict__ ht, float* __restrict__ q1,
    int b0)
{
    const int t = threadIdx.x;
    const int bl = blockIdx.x, b = b0 + bl;
    __shared__ float Xs[64][260];
    __shared__ float Ys[64][132];
    __shared__ int s_alias[64];
    __shared__ float s_rn[64];
    __shared__ int s_last;

    if (t < 64) s_alias[t] = alias[b*64 + t];
    __syncthreads();
    if (t == 0){
        int cnt = 0;
        for (int l = 0; l < 64; ++l) cnt += (s_alias[l] > 0) ? 1 : 0;
        s_last = (cnt - 1) & 63;
    }
    #pragma unroll
    for (int c = 0; c < 8; ++c){
        int flat = c*1024 + t*4;
        int l = flat >> 7, k = flat & 127;
        *(float4*)&Xs[l][k] = *(const float4*)(pos + l*128 + k);
        int row = s_alias[l];
        *(float4*)&Xs[l][128+k] = *(const float4*)(hn + (size_t)(bl*64 + row)*128 + k);
    }
    __syncthreads();

    const int tc = t & 31, tr = t >> 5;
    float acc[8][4];
    #pragma unroll
    for (int i=0;i<8;i++){ acc[i][0]=0.f; acc[i][1]=0.f; acc[i][2]=0.f; acc[i][3]=0.f; }

    for (int k = 0; k < 256; k += 4){
        float4 w0 = *(const float4*)(lp + (size_t)(k+0)*128 + tc*4);
        float4 w1 = *(const float4*)(lp + (size_t)(k+1)*128 + tc*4);
        float4 w2 = *(const float4*)(lp + (size_t)(k+2)*128 + tc*4);
        float4 w3 = *(const float4*)(lp + (size_t)(k+3)*128 + tc*4);
        #pragma unroll
        for (int i = 0; i < 8; ++i){
            float4 a4 = *(const float4*)&Xs[tr*8+i][k];
            acc[i][0] += a4.x*w0.x + a4.y*w1.x + a4.z*w2.x + a4.w*w3.x;
            acc[i][1] += a4.x*w0.y + a4.y*w1.y + a4.z*w2.y + a4.w*w3.y;
            acc[i][2] += a4.x*w0.z + a4.y*w1.z + a4.z*w2.z + a4.w*w3.z;
            acc[i][3] += a4.x*w0.w + a4.y*w1.w + a4.z*w2.w + a4.w*w3.w;
        }
    }
    #pragma unroll
    for (int i = 0; i < 8; ++i){
        float4 o;
        o.x = tanhf(acc[i][0]); o.y = tanhf(acc[i][1]);
        o.z = tanhf(acc[i][2]); o.w = tanhf(acc[i][3]);
        *(float4*)&Ys[tr*8+i][tc*4] = o;
    }
    __syncthreads();
    if (t < 64){
        float s = 0.f;
        #pragma unroll 8
        for (int k = 0; k < 128; ++k){ float v = Ys[t][k]; s = fmaf(v, v, s); }
        s_rn[t] = rsqrtf(s);
    }
    __syncthreads();
    #pragma unroll
    for (int c = 0; c < 8; ++c){
        int flat = c*1024 + t*4;
        int l = flat >> 7, k = flat & 127;
        float rn = s_rn[l];
        float4 o;
        o.x = Ys[l][k+0]*rn; o.y = Ys[l][k+1]*rn; o.z = Ys[l][k+2]*rn; o.w = Ys[l][k+3]*rn;
        *(float4*)(seq + (size_t)(bl*64 + l)*128 + k) = o;
    }
    if (t < 128){
        int h = t;
        int lst = s_last;
        float rn = s_rn[lst];
        float hv = Ys[lst][h]*rn;
        ht[(size_t)b*128 + h] = hv;
        float o = b1[h];
        const float* wr = W1 + (size_t)h*128;
        #pragma unroll 8
        for (int k = 0; k < 128; ++k) o += (Ys[lst][k]*rn) * wr[k];
        q1[(size_t)b*128 + h] = o;
    }
}

// ---------------- attention + final projection a_final ----------------
__global__ __launch_bounds__(256) void k_attn(
    const int* __restrict__ alias, const float* __restrict__ seq,
    const float* __restrict__ q2m, const float* __restrict__ q1,
    const float* __restrict__ ht, const float* __restrict__ W3,
    const float* __restrict__ Wt, const float* __restrict__ bt,
    float* __restrict__ afin, int b0)
{
    const int t = threadIdx.x;
    const int bl = blockIdx.x, b = b0 + bl;
    __shared__ float s_seq[64][132];
    __shared__ float s_q2[64][132];
    __shared__ float s_q1[128], s_ht[128];
    __shared__ float s_part[64][4];
    __shared__ float s_alpha[64];
    __shared__ float s_a[128];
    __shared__ int s_alias2[64];

    if (t < 64) s_alias2[t] = alias[b*64 + t];
    if (t < 128){ s_q1[t] = q1[(size_t)b*128 + t]; s_ht[t] = ht[(size_t)b*128 + t]; }
    #pragma unroll
    for (int c = 0; c < 8; ++c){
        int flat = c*1024 + t*4;
        int l = flat >> 7, k = flat & 127;
        *(float4*)&s_seq[l][k] = *(const float4*)(seq + (size_t)(bl*64 + l)*128 + k);
        *(float4*)&s_q2[l][k]  = *(const float4*)(q2m + (size_t)(bl*64 + l)*128 + k);
    }
    __syncthreads();
    {
        int l = t >> 2, gq = t & 3;
        float p = 0.f;
        #pragma unroll 8
        for (int hh = 0; hh < 32; ++hh){
            int h = gq*32 + hh;
            float sv = sigmoidf_(s_q1[h] + s_q2[l][h]);
            p += sv * W3[h];
        }
        s_part[l][gq] = p;
    }
    __syncthreads();
    if (t < 64){
        float al = s_part[t][0] + s_part[t][1] + s_part[t][2] + s_part[t][3];
        s_alpha[t] = (s_alias2[t] > 0) ? al : 0.f;
    }
    __syncthreads();
    if (t < 128){
        float a_ = 0.f;
        #pragma unroll 8
        for (int l = 0; l < 64; ++l) a_ += s_alpha[l]*s_seq[l][t];
        s_a[t] = a_;
    }
    __syncthreads();
    if (t < 128){
        int h = t;
        float o = bt[h];
        const float* wr = Wt + (size_t)h*256;
        #pragma unroll 8
        for (int k = 0; k < 128; ++k) o += s_a[k]*wr[k];
        #pragma unroll 8
        for (int k = 0; k < 128; ++k) o += s_ht[k]*wr[128+k];
        afin[(size_t)b*128 + h] = o;
    }
}

// ---------------- prep: afin f32 -> bf16 hi/lo A-fragments ----------------
__global__ __launch_bounds__(256) void k_prep_pred(
    const float* __restrict__ afin, unsigned short* __restrict__ Ahi,
    unsigned short* __restrict__ Alo)
{
    int idx = blockIdx.x*256 + threadIdx.x;
    int lane = idx & 63;
    int tile = idx >> 6;
    int mt = tile >> 2, ks = tile & 3;
    int row = mt*16 + (lane & 15);
    int k0  = ks*32 + (lane >> 4)*8;
    const float* src = afin + (size_t)row*128 + k0;
    float4 f0 = *(const float4*)(src);
    float4 f1 = *(const float4*)(src + 4);
    float xs[8] = {f0.x,f0.y,f0.z,f0.w,f1.x,f1.y,f1.z,f1.w};
    short8v h,l; split8(xs,h,l);
    *(short8v*)(Ahi + (size_t)idx*8) = h;
    *(short8v*)(Alo + (size_t)idx*8) = l;
}

// ---------------- pred = 16 * afin @ emb[1:]^T  via MFMA bf16 split ----------------
#define NVOCAB 99999
__global__ __launch_bounds__(256) void k_pred_mfma(
    const unsigned short* __restrict__ Ahi, const unsigned short* __restrict__ Alo,
    const float* __restrict__ emb, float* __restrict__ outp)
{
    const int t = threadIdx.x;
    const int lane = t & 63;
    const int w = t >> 6;
    const int cb = blockIdx.x * 64;

    __shared__ float s_e[64][132];

    #pragma unroll
    for (int c = 0; c < 8; ++c){
        int flat4 = c*256 + t;
        int row = flat4 >> 5;
        int k4  = (flat4 & 31) * 4;
        int v = cb + row;
        int srow = (v < NVOCAB) ? (v + 1) : 0;
        *(float4*)&s_e[row][k4] = *(const float4*)(emb + (size_t)srow*128 + k4);
    }
    __syncthreads();

    short8v bhi[4][4], blo[4][4];
    {
        const int col = lane & 15;
        const int kg  = (lane >> 4) * 8;
        #pragma unroll
        for (int nt = 0; nt < 4; ++nt){
            #pragma unroll
            for (int ks = 0; ks < 4; ++ks){
                const float* p = &s_e[nt*16 + col][ks*32 + kg];
                float4 f0 = *(const float4*)(p);
                float4 f1 = *(const float4*)(p + 4);
                float xs[8] = {f0.x,f0.y,f0.z,f0.w,f1.x,f1.y,f1.z,f1.w};
                short8v h, l; split8(xs,h,l);
                bhi[nt][ks] = h; blo[nt][ks] = l;
            }
        }
    }

    for (int mt = w; mt < 32; mt += 4){
        short8v ahi[4], alo[4];
        #pragma unroll
        for (int ks = 0; ks < 4; ++ks){
            size_t off = ((size_t)(mt*4 + ks)*64 + lane)*8;
            ahi[ks] = *(const short8v*)(Ahi + off);
            alo[ks] = *(const short8v*)(Alo + off);
        }
        const int r0 = mt*16 + (lane >> 4)*4;
        const int colrel = lane & 15;
        #pragma unroll
        for (int nt = 0; nt < 4; ++nt){
            f32x4 acc = {0.f, 0.f, 0.f, 0.f};
            #pragma unroll
            for (int ks = 0; ks < 4; ++ks){
                acc = __builtin_amdgcn_mfma_f32_16x16x32_bf16(ahi[ks], bhi[nt][ks], acc, 0, 0, 0);
                acc = __builtin_amdgcn_mfma_f32_16x16x32_bf16(alo[ks], bhi[nt][ks], acc, 0, 0, 0);
                acc = __builtin_amdgcn_mfma_f32_16x16x32_bf16(ahi[ks], blo[nt][ks], acc, 0, 0, 0);
            }
            int col = cb + nt*16 + colrel;
            if (col < NVOCAB){
                #pragma unroll
                for (int j = 0; j < 4; ++j)
                    outp[(size_t)(r0 + j)*NVOCAB + col] = 16.0f * acc[j];
            }
        }
    }
}

extern "C" void kernel_launch(void* const* d_in, const int* in_sizes, int n_in,
                              void* d_out, int out_size, void* d_ws, size_t ws_size,
                              hipStream_t stream)
{
    const int*   items = (const int*)  d_in[0];
    const float* Amat  = (const float*)d_in[1];
    const int*   alias = (const int*)  d_in[2];
    const float* emb   = (const float*)d_in[3];
    const float* pos   = (const float*)d_in[4];
    const float* lp    = (const float*)d_in[5];
    const float* w_ih  = (const float*)d_in[6];
    const float* w_hh  = (const float*)d_in[7];
    const float* b_ih  = (const float*)d_in[8];
    const float* b_hh  = (const float*)d_in[9];
    const float* b_iah = (const float*)d_in[10];
    const float* b_oah = (const float*)d_in[11];
    const float* W_in  = (const float*)d_in[12];
    const float* b_in  = (const float*)d_in[13];
    const float* W_out = (const float*)d_in[14];
    const float* b_out = (const float*)d_in[15];
    const float* W1    = (const float*)d_in[16];
    const float* b1    = (const float*)d_in[17];
    const float* W2    = (const float*)d_in[18];
    const float* b2    = (const float*)d_in[19];
    const float* W3    = (const float*)d_in[20];
    const float* Wt    = (const float*)d_in[21];
    const float* bt    = (const float*)d_in[22];
    float* outp = (float*)d_out;

    // ---- workspace carve ----
    float* wsf = (float*)d_ws;
    float* W2T    = wsf;                   size_t o = 16384;
    float* htb    = wsf + o;               o += 65536;
    float* q1b    = wsf + o;               o += 65536;
    float* afin   = wsf + o;               o += 65536;
    float* hidden = wsf + o;               o += 4194304;
    float* hidnew = wsf + o;               o += 4194304;
    float* seqb   = wsf + o;               o += 4194304;
    float* q2b    = wsf + o;               o += 4194304;
    unsigned short* us = (unsigned short*)(wsf + o);
    size_t uo = 0;
    unsigned short* wo_hi  = us + uo; uo += 32768;
    unsigned short* wo_lo  = us + uo; uo += 32768;
    unsigned short* wih_hi = us + uo; uo += 98304;
    unsigned short* wih_lo = us + uo; uo += 98304;
    unsigned short* whh_hi = us + uo; uo += 49152;
    unsigned short* whh_lo = us + uo; uo += 49152;
    unsigned short* pA_hi  = us + uo; uo += 65536;
    unsigned short* pA_lo  = us + uo; uo += 65536;
    unsigned short* hidf_hi= us + uo; uo += 4194304;
    unsigned short* hidf_lo= us + uo; uo += 4194304;
    unsigned short* inpf_hi= us + uo; uo += 8388608;
    unsigned short* inpf_lo= us + uo; uo += 8388608;

    ktrans<<<64, 256, 0, stream>>>(W2, W2T, 128, 128);
    k_prep_wfrag<<<88, 256, 0, stream>>>(W_in, W_out, w_ih, w_hh,
                                         wo_hi, wo_lo, wih_hi, wih_lo, whh_hi, whh_lo);
    k_gnn1<<<512, 256, 0, stream>>>(items, Amat, emb, b_in, b_out, b_iah, b_oah,
                                    wo_hi, wo_lo, hidden, hidf_hi, hidf_lo, inpf_hi, inpf_lo);
    k_gru<<<256, 512, 0, stream>>>(inpf_hi, inpf_lo, hidf_hi, hidf_lo,
                                   wih_hi, wih_lo, whh_hi, whh_lo, b_ih, b_hh, hidden, hidnew);
    k_seq<<<512, 256, 0, stream>>>(alias, pos, lp, hidnew, W1, b1, seqb, htb, q1b, 0);
    k_gemm<<<dim3(1, 512), 256, 0, stream>>>(seqb, W2T, b2, q2b, 32768, 128, 128);
    k_attn<<<512, 256, 0, stream>>>(alias, seqb, q2b, q1b, htb, W3, Wt, bt, afin, 0);
    k_prep_pred<<<32, 256, 0, stream>>>(afin, pA_hi, pA_lo);
    k_pred_mfma<<<(NVOCAB + 63)/64, 256, 0, stream>>>(pA_hi, pA_lo, emb, outp);
}

// Round 4
// 393.910 us; speedup vs baseline: 2.0032x; 1.2908x over previous
//
#include <hip/hip_runtime.h>
#include <cstddef>
#include <cstdint>

#define NVOCAB 99999

typedef __attribute__((ext_vector_type(8))) short short8v;
typedef __attribute__((ext_vector_type(4))) short short4v;
typedef __attribute__((ext_vector_type(4))) float f32x4;

__device__ __forceinline__ float sigmoidf_(float x){ return 1.0f/(1.0f + __expf(-x)); }

__device__ __forceinline__ unsigned short bf16rn(float x){
    union { float f; uint32_t u; } v; v.f = x;
    uint32_t r = v.u + 0x7FFFu + ((v.u >> 16) & 1u);
    return (unsigned short)(r >> 16);
}

__device__ __forceinline__ void split_bf16(float x, unsigned short &hi, unsigned short &lo){
    hi = bf16rn(x);
    union { uint32_t u; float f; } hf; hf.u = ((uint32_t)hi) << 16;
    lo = bf16rn(x - hf.f);
}

__device__ __forceinline__ void split8(const float* xs, short8v &h, short8v &l){
    #pragma unroll
    for (int e = 0; e < 8; ++e){
        unsigned short uh, ul;
        split_bf16(xs[e], uh, ul);
        h[e] = (short)uh; l[e] = (short)ul;
    }
}

// ---------------- generic transpose (tiny weights only) ----------------
__global__ void ktrans(const float* __restrict__ src, float* __restrict__ dst, int R, int C)
{
    int idx = blockIdx.x*256 + threadIdx.x;
    if (idx < R*C){ int r = idx / C; int c = idx - r*C; dst[c*R + r] = src[idx]; }
}

// ---------------- prep: split weights into B-fragment layout ----------------
__global__ __launch_bounds__(256) void k_prep_wfrag(
    const float* __restrict__ W_in, const float* __restrict__ W_out,
    const float* __restrict__ w_ih, const float* __restrict__ w_hh,
    unsigned short* __restrict__ wo_hi, unsigned short* __restrict__ wo_lo,
    unsigned short* __restrict__ wih_hi, unsigned short* __restrict__ wih_lo,
    unsigned short* __restrict__ whh_hi, unsigned short* __restrict__ whh_lo)
{
    int id = blockIdx.x*256 + threadIdx.x;
    const float* src; unsigned short *dh, *dl;
    if (id < 4096){
        int lane=id&63, tile=id>>6, nt=tile>>2, ks=tile&3;
        int col=nt*16+(lane&15), k=ks*32+(lane>>4)*8;
        src = (col<128) ? (W_in + (size_t)col*128 + k) : (W_out + (size_t)(col-128)*128 + k);
        dh=wo_hi+(size_t)id*8; dl=wo_lo+(size_t)id*8;
    } else if (id < 16384){
        int t2=id-4096, lane=t2&63, tile=t2>>6, nt=tile>>3, ks=tile&7;
        int col=nt*16+(lane&15), k=ks*32+(lane>>4)*8;
        src = w_ih + (size_t)col*256 + k;
        dh=wih_hi+(size_t)t2*8; dl=wih_lo+(size_t)t2*8;
    } else if (id < 22528){
        int t3=id-16384, lane=t3&63, tile=t3>>6, nt=tile>>2, ks=tile&3;
        int col=nt*16+(lane&15), k=ks*32+(lane>>4)*8;
        src = w_hh + (size_t)col*128 + k;
        dh=whh_hi+(size_t)t3*8; dl=whh_lo+(size_t)t3*8;
    } else return;
    float4 f0=*(const float4*)src, f1=*(const float4*)(src+4);
    float xs[8]={f0.x,f0.y,f0.z,f0.w,f1.x,f1.y,f1.z,f1.w};
    short8v h,l; split8(xs,h,l);
    *(short8v*)dh = h; *(short8v*)dl = l;
}

// ---------------- prep: emb -> bf16 B-fragments (hi only) ----------------
// Ebf[(((vt*4+nt)*4+ks)*64 + lane)*8 + e] = bf16(emb[row(col)+1][k]),
//   col = vt*64+nt*16+(lane&15), k = ks*32+(lane>>4)*8+e
__global__ __launch_bounds__(256) void k_prep_embf(
    const float* __restrict__ emb, unsigned short* __restrict__ Ebf)
{
    int idx = blockIdx.x*256 + threadIdx.x;
    int v = idx >> 4;
    if (v >= 100032) return;
    int o = idx & 15;
    int srcr = (v < NVOCAB) ? (v+1) : 0;
    const float* src = emb + (size_t)srcr*128 + o*8;
    float4 f0=*(const float4*)src, f1=*(const float4*)(src+4);
    float xs[8]={f0.x,f0.y,f0.z,f0.w,f1.x,f1.y,f1.z,f1.w};
    short8v h;
    #pragma unroll
    for (int e=0;e<8;++e) h[e]=(short)bf16rn(xs[e]);
    int vt=v>>6, c=v&63, nt=c>>4, c15=c&15, ks=o>>2, gq=o&3;
    int lanez = gq*16 + c15;
    size_t off = (((size_t)vt*16 + nt*4 + ks)*64 + lanez)*8;
    *(short8v*)(Ebf + off) = h;
}

// ---------------- K1: gather + hv GEMM + bmm, emit hidden f32 + A-frag splits ----------------
union SharedU {
    struct { unsigned short hi[256][72]; unsigned short lo[256][72]; } hvT;
    float inp[64][268];
};

__global__ __launch_bounds__(256) void k_gnn1(
    const int* __restrict__ items, const float* __restrict__ Amat,
    const float* __restrict__ emb,
    const float* __restrict__ b_in, const float* __restrict__ b_out,
    const float* __restrict__ b_iah, const float* __restrict__ b_oah,
    const unsigned short* __restrict__ wo_hi, const unsigned short* __restrict__ wo_lo,
    float* __restrict__ hidden,
    unsigned short* __restrict__ hid_hi, unsigned short* __restrict__ hid_lo,
    unsigned short* __restrict__ inp_hi, unsigned short* __restrict__ inp_lo)
{
    const int t=threadIdx.x, lane=t&63, w=t>>6, bl=blockIdx.x;
    const int c15=lane&15, g=lane>>4, kg=g*8;
    const int mt=w;
    const int row=mt*16+c15;

    __shared__ int s_items[64];
    __shared__ SharedU U;

    if (t < 64) s_items[t]=items[bl*64+t];
    __syncthreads();

    short8v hhi[4], hlo[4];
    {
        const float* src = emb + (size_t)s_items[row]*128;
        float* hd = hidden + (size_t)(bl*64+row)*128;
        #pragma unroll
        for (int ks=0; ks<4; ++ks){
            float4 f0=*(const float4*)(src+ks*32+kg);
            float4 f1=*(const float4*)(src+ks*32+kg+4);
            *(float4*)(hd+ks*32+kg)=f0; *(float4*)(hd+ks*32+kg+4)=f1;
            float xs[8]={f0.x,f0.y,f0.z,f0.w,f1.x,f1.y,f1.z,f1.w};
            short8v h,l; split8(xs,h,l);
            hhi[ks]=h; hlo[ks]=l;
            size_t off=((size_t)(bl*4+mt)*4+ks)*512 + lane*8;
            *(short8v*)(hid_hi+off)=h; *(short8v*)(hid_lo+off)=l;
        }
    }

    f32x4 acc[16];
    #pragma unroll
    for (int nt=0;nt<16;++nt){
        int col=nt*16+c15;
        float bv=(col<128)? b_in[col] : b_out[col-128];
        acc[nt]=(f32x4){bv,bv,bv,bv};
    }
    for (int ks=0; ks<4; ++ks){
        #pragma unroll
        for (int nt=0; nt<16; ++nt){
            size_t wo=((size_t)(nt*4+ks)*64+lane)*8;
            short8v bh=*(const short8v*)(wo_hi+wo);
            short8v bl_=*(const short8v*)(wo_lo+wo);
            acc[nt]=__builtin_amdgcn_mfma_f32_16x16x32_bf16(hhi[ks],bh,acc[nt],0,0,0);
            acc[nt]=__builtin_amdgcn_mfma_f32_16x16x32_bf16(hlo[ks],bh,acc[nt],0,0,0);
            acc[nt]=__builtin_amdgcn_mfma_f32_16x16x32_bf16(hhi[ks],bl_,acc[nt],0,0,0);
        }
    }

    {
        const int r0=g*4;
        #pragma unroll
        for (int nt=0;nt<16;++nt){
            int col=nt*16+c15;
            short4v h4,l4;
            #pragma unroll
            for (int j=0;j<4;++j){
                unsigned short uh,ul; split_bf16(acc[nt][j],uh,ul);
                h4[j]=(short)uh; l4[j]=(short)ul;
            }
            *(short4v*)&U.hvT.hi[col][mt*16+r0] = h4;
            *(short4v*)&U.hvT.lo[col][mt*16+r0] = l4;
        }
    }
    __syncthreads();

    f32x4 acc2[16];
    #pragma unroll
    for (int nt=0;nt<16;++nt){
        int col=nt*16+c15;
        float bv=(col<128)? b_iah[col] : b_oah[col-128];
        acc2[nt]=(f32x4){bv,bv,bv,bv};
    }
    short8v aihi[2],ailo[2],aohi[2],aolo[2];
    {
        const float* Ab = Amat + (size_t)bl*8192 + (size_t)row*128;
        #pragma unroll
        for (int ks=0;ks<2;++ks){
            float4 f0=*(const float4*)(Ab+ks*32+kg);
            float4 f1=*(const float4*)(Ab+ks*32+kg+4);
            float xs[8]={f0.x,f0.y,f0.z,f0.w,f1.x,f1.y,f1.z,f1.w};
            split8(xs,aihi[ks],ailo[ks]);
            float4 g0=*(const float4*)(Ab+64+ks*32+kg);
            float4 g1=*(const float4*)(Ab+64+ks*32+kg+4);
            float ys[8]={g0.x,g0.y,g0.z,g0.w,g1.x,g1.y,g1.z,g1.w};
            split8(ys,aohi[ks],aolo[ks]);
        }
    }
    for (int ks=0;ks<2;++ks){
        #pragma unroll
        for (int nt=0;nt<16;++nt){
            int h=nt*16+c15;
            int m0=ks*32+kg;
            short8v bh=*(const short8v*)&U.hvT.hi[h][m0];
            short8v bl_=*(const short8v*)&U.hvT.lo[h][m0];
            short8v ah=(nt<8)?aihi[ks]:aohi[ks];
            short8v al=(nt<8)?ailo[ks]:aolo[ks];
            acc2[nt]=__builtin_amdgcn_mfma_f32_16x16x32_bf16(ah,bh,acc2[nt],0,0,0);
            acc2[nt]=__builtin_amdgcn_mfma_f32_16x16x32_bf16(al,bh,acc2[nt],0,0,0);
            acc2[nt]=__builtin_amdgcn_mfma_f32_16x16x32_bf16(ah,bl_,acc2[nt],0,0,0);
        }
    }
    __syncthreads();

    {
        #pragma unroll
        for (int nt=0;nt<16;++nt){
            int col=nt*16+c15;
            #pragma unroll
            for (int j=0;j<4;++j)
                U.inp[mt*16+g*4+j][col]=acc2[nt][j];
        }
    }
    __syncthreads();

    {
        #pragma unroll
        for (int ks=0;ks<8;++ks){
            float4 f0=*(const float4*)&U.inp[row][ks*32+kg];
            float4 f1=*(const float4*)&U.inp[row][ks*32+kg+4];
            float xs[8]={f0.x,f0.y,f0.z,f0.w,f1.x,f1.y,f1.z,f1.w};
            short8v h,l; split8(xs,h,l);
            size_t off=((size_t)(bl*4+mt)*8+ks)*512 + lane*8;
            *(short8v*)(inp_hi+off)=h; *(short8v*)(inp_lo+off)=l;
        }
    }
}

// ---------------- K2: gi/gh GEMMs + GRU gate (2 waves per row-tile, no spill) ----------------
__global__ __launch_bounds__(512,1) void k_gru(
    const unsigned short* __restrict__ inp_hi, const unsigned short* __restrict__ inp_lo,
    const unsigned short* __restrict__ hid_hi, const unsigned short* __restrict__ hid_lo,
    const unsigned short* __restrict__ wih_hi, const unsigned short* __restrict__ wih_lo,
    const unsigned short* __restrict__ whh_hi, const unsigned short* __restrict__ whh_lo,
    const float* __restrict__ b_ih, const float* __restrict__ b_hh,
    const float* __restrict__ hidden, float* __restrict__ hidnew)
{
    const int t=threadIdx.x, lane=t&63, w=t>>6;
    const int wh = w & 1;                       // column half
    const int gmt = blockIdx.x*4 + (w>>1);      // row tile (16 rows)
    const int c15=lane&15, g=lane>>4;

    __shared__ unsigned short wbuf[2][24][1024];

    auto stage=[&](int ks, int buf){
        #pragma unroll
        for (int i=0;i<3;++i){
            int idx=i*512+t;
            int nt=idx>>6, ln=idx&63;
            const unsigned short *sh, *sl;
            if (ks<4){ size_t o=((size_t)(nt*4+ks)*64+ln)*8; sh=whh_hi+o; sl=whh_lo+o; }
            else     { size_t o=((size_t)(nt*8+(ks-4))*64+ln)*8; sh=wih_hi+o; sl=wih_lo+o; }
            *(short8v*)&wbuf[buf][nt][ln*8]     = *(const short8v*)sh;
            *(short8v*)&wbuf[buf][nt][512+ln*8] = *(const short8v*)sl;
        }
    };

    // wave covers nt = tg*8 + wh*4 + sub for tg in 0..2, sub in 0..3 (j = tg*4+sub)
    f32x4 agi[12], agh[12];
    #pragma unroll
    for (int j=0;j<12;++j){
        int nt=(j>>2)*8 + wh*4 + (j&3);
        int col=nt*16+c15;
        float bi=b_ih[col], bh=b_hh[col];
        agi[j]=(f32x4){bi,bi,bi,bi};
        agh[j]=(f32x4){bh,bh,bh,bh};
    }

    stage(0,0);
    __syncthreads();
    for (int ks=0; ks<12; ++ks){
        int buf=ks&1;
        if (ks<11) stage(ks+1, buf^1);
        short8v ah, al;
        if (ks<4){
            size_t o=((size_t)gmt*4+ks)*512 + (size_t)lane*8;
            ah=*(const short8v*)(hid_hi+o); al=*(const short8v*)(hid_lo+o);
        } else {
            size_t o=((size_t)gmt*8+(ks-4))*512 + (size_t)lane*8;
            ah=*(const short8v*)(inp_hi+o); al=*(const short8v*)(inp_lo+o);
        }
        if (ks<4){
            #pragma unroll
            for (int j=0;j<12;++j){
                int nt=(j>>2)*8 + wh*4 + (j&3);
                short8v bh=*(const short8v*)&wbuf[buf][nt][lane*8];
                short8v bl_=*(const short8v*)&wbuf[buf][nt][512+lane*8];
                agh[j]=__builtin_amdgcn_mfma_f32_16x16x32_bf16(ah,bh,agh[j],0,0,0);
                agh[j]=__builtin_amdgcn_mfma_f32_16x16x32_bf16(al,bh,agh[j],0,0,0);
                agh[j]=__builtin_amdgcn_mfma_f32_16x16x32_bf16(ah,bl_,agh[j],0,0,0);
            }
        } else {
            #pragma unroll
            for (int j=0;j<12;++j){
                int nt=(j>>2)*8 + wh*4 + (j&3);
                short8v bh=*(const short8v*)&wbuf[buf][nt][lane*8];
                short8v bl_=*(const short8v*)&wbuf[buf][nt][512+lane*8];
                agi[j]=__builtin_amdgcn_mfma_f32_16x16x32_bf16(ah,bh,agi[j],0,0,0);
                agi[j]=__builtin_amdgcn_mfma_f32_16x16x32_bf16(al,bh,agi[j],0,0,0);
                agi[j]=__builtin_amdgcn_mfma_f32_16x16x32_bf16(ah,bl_,agi[j],0,0,0);
            }
        }
        __syncthreads();
    }

    // fused GRU gate: wave's columns are h = (wh*4+sub)*16 + c15
    const int r0=gmt*16+g*4;
    #pragma unroll
    for (int sub=0;sub<4;++sub){
        int h=(wh*4+sub)*16+c15;
        #pragma unroll
        for (int j2=0;j2<4;++j2){
            float ir=agi[sub][j2], ii=agi[4+sub][j2], in_=agi[8+sub][j2];
            float hr=agh[sub][j2], hi_=agh[4+sub][j2], hn=agh[8+sub][j2];
            float rg=sigmoidf_(ir+hr), ig=sigmoidf_(ii+hi_);
            float ng=tanhf(in_+rg*hn);
            float ho=hidden[(size_t)(r0+j2)*128+h];
            hidnew[(size_t)(r0+j2)*128+h]=ng+ig*(ho-ng);
        }
    }
}

// ---------------- generic fp32 GEMM (kept for q2) ----------------
__global__ __launch_bounds__(256) void k_gemm(
    const float* __restrict__ A, const float* __restrict__ Bt,
    const float* __restrict__ bias, float* __restrict__ C,
    int M, int N, int K)
{
    const int t = threadIdx.x;
    const int tc = t & 31, tr = t >> 5;
    const int rb = blockIdx.y * 64;
    const int cb = blockIdx.x * 128;

    __shared__ float As[64][36];
    __shared__ float Ws[32][132];

    float acc[8][4];
    {
        float4 bv = *(const float4*)(bias + cb + tc*4);
        #pragma unroll
        for (int i = 0; i < 8; ++i){ acc[i][0]=bv.x; acc[i][1]=bv.y; acc[i][2]=bv.z; acc[i][3]=bv.w; }
    }

    for (int kc = 0; kc < K; kc += 32){
        int arow = t >> 2;
        int ak0  = (t & 3) * 8;
        const float* asrc = A + (size_t)(rb + arow)*K + kc + ak0;
        float4 av0 = *(const float4*)(asrc);
        float4 av1 = *(const float4*)(asrc + 4);
        int wk  = t >> 3;
        int wc0 = (t & 7) * 16;
        const float* wsrc = Bt + (size_t)(kc + wk)*N + cb + wc0;
        float4 wv0 = *(const float4*)(wsrc);
        float4 wv1 = *(const float4*)(wsrc + 4);
        float4 wv2 = *(const float4*)(wsrc + 8);
        float4 wv3 = *(const float4*)(wsrc + 12);
        __syncthreads();
        *(float4*)&As[arow][ak0]   = av0;
        *(float4*)&As[arow][ak0+4] = av1;
        *(float4*)&Ws[wk][wc0]     = wv0;
        *(float4*)&Ws[wk][wc0+4]   = wv1;
        *(float4*)&Ws[wk][wc0+8]   = wv2;
        *(float4*)&Ws[wk][wc0+12]  = wv3;
        __syncthreads();
        #pragma unroll
        for (int k = 0; k < 32; ++k){
            float4 wv = *(const float4*)&Ws[k][tc*4];
            #pragma unroll
            for (int i = 0; i < 8; ++i){
                float a_ = As[tr*8+i][k];
                acc[i][0] += a_*wv.x; acc[i][1] += a_*wv.y;
                acc[i][2] += a_*wv.z; acc[i][3] += a_*wv.w;
            }
        }
    }
    #pragma unroll
    for (int i = 0; i < 8; ++i){
        float4 o; o.x=acc[i][0]; o.y=acc[i][1]; o.z=acc[i][2]; o.w=acc[i][3];
        *(float4*)(C + (size_t)(rb + tr*8 + i)*N + cb + tc*4) = o;
    }
}

// ---------------- seq ----------------
__global__ __launch_bounds__(256) void k_seq(
    const int* __restrict__ alias, const float* __restrict__ pos,
    const float* __restrict__ lp, const float* __restrict__ hn,
    const float* __restrict__ W1, const float* __restrict__ b1,
    float* __restrict__ seq, float* __restrict__ ht, float* __restrict__ q1,
    int b0)
{
    const int t = threadIdx.x;
    const int bl = blockIdx.x, b = b0 + bl;
    __shared__ float Xs[64][260];
    __shared__ float Ys[64][132];
    __shared__ int s_alias[64];
    __shared__ float s_rn[64];
    __shared__ int s_last;

    if (t < 64) s_alias[t] = alias[b*64 + t];
    __syncthreads();
    if (t == 0){
        int cnt = 0;
        for (int l = 0; l < 64; ++l) cnt += (s_alias[l] > 0) ? 1 : 0;
        s_last = (cnt - 1) & 63;
    }
    #pragma unroll
    for (int c = 0; c < 8; ++c){
        int flat = c*1024 + t*4;
        int l = flat >> 7, k = flat & 127;
        *(float4*)&Xs[l][k] = *(const float4*)(pos + l*128 + k);
        int row = s_alias[l];
        *(float4*)&Xs[l][128+k] = *(const float4*)(hn + (size_t)(bl*64 + row)*128 + k);
    }
    __syncthreads();

    const int tc = t & 31, tr = t >> 5;
    float acc[8][4];
    #pragma unroll
    for (int i=0;i<8;i++){ acc[i][0]=0.f; acc[i][1]=0.f; acc[i][2]=0.f; acc[i][3]=0.f; }

    for (int k = 0; k < 256; k += 4){
        float4 w0 = *(const float4*)(lp + (size_t)(k+0)*128 + tc*4);
        float4 w1 = *(const float4*)(lp + (size_t)(k+1)*128 + tc*4);
        float4 w2 = *(const float4*)(lp + (size_t)(k+2)*128 + tc*4);
        float4 w3 = *(const float4*)(lp + (size_t)(k+3)*128 + tc*4);
        #pragma unroll
        for (int i = 0; i < 8; ++i){
            float4 a4 = *(const float4*)&Xs[tr*8+i][k];
            acc[i][0] += a4.x*w0.x + a4.y*w1.x + a4.z*w2.x + a4.w*w3.x;
            acc[i][1] += a4.x*w0.y + a4.y*w1.y + a4.z*w2.y + a4.w*w3.y;
            acc[i][2] += a4.x*w0.z + a4.y*w1.z + a4.z*w2.z + a4.w*w3.z;
            acc[i][3] += a4.x*w0.w + a4.y*w1.w + a4.z*w2.w + a4.w*w3.w;
        }
    }
    #pragma unroll
    for (int i = 0; i < 8; ++i){
        float4 o;
        o.x = tanhf(acc[i][0]); o.y = tanhf(acc[i][1]);
        o.z = tanhf(acc[i][2]); o.w = tanhf(acc[i][3]);
        *(float4*)&Ys[tr*8+i][tc*4] = o;
    }
    __syncthreads();
    if (t < 64){
        float s = 0.f;
        #pragma unroll 8
        for (int k = 0; k < 128; ++k){ float v = Ys[t][k]; s = fmaf(v, v, s); }
        s_rn[t] = rsqrtf(s);
    }
    __syncthreads();
    #pragma unroll
    for (int c = 0; c < 8; ++c){
        int flat = c*1024 + t*4;
        int l = flat >> 7, k = flat & 127;
        float rn = s_rn[l];
        float4 o;
        o.x = Ys[l][k+0]*rn; o.y = Ys[l][k+1]*rn; o.z = Ys[l][k+2]*rn; o.w = Ys[l][k+3]*rn;
        *(float4*)(seq + (size_t)(bl*64 + l)*128 + k) = o;
    }
    if (t < 128){
        int h = t;
        int lst = s_last;
        float rn = s_rn[lst];
        float hv = Ys[lst][h]*rn;
        ht[(size_t)b*128 + h] = hv;
        float o = b1[h];
        const float* wr = W1 + (size_t)h*128;
        #pragma unroll 8
        for (int k = 0; k < 128; ++k) o += (Ys[lst][k]*rn) * wr[k];
        q1[(size_t)b*128 + h] = o;
    }
}

// ---------------- attention + final projection ----------------
__global__ __launch_bounds__(256) void k_attn(
    const int* __restrict__ alias, const float* __restrict__ seq,
    const float* __restrict__ q2m, const float* __restrict__ q1,
    const float* __restrict__ ht, const float* __restrict__ W3,
    const float* __restrict__ Wt, const float* __restrict__ bt,
    float* __restrict__ afin, int b0)
{
    const int t = threadIdx.x;
    const int bl = blockIdx.x, b = b0 + bl;
    __shared__ float s_seq[64][132];
    __shared__ float s_q2[64][132];
    __shared__ float s_q1[128], s_ht[128];
    __shared__ float s_part[64][4];
    __shared__ float s_alpha[64];
    __shared__ float s_a[128];
    __shared__ int s_alias2[64];

    if (t < 64) s_alias2[t] = alias[b*64 + t];
    if (t < 128){ s_q1[t] = q1[(size_t)b*128 + t]; s_ht[t] = ht[(size_t)b*128 + t]; }
    #pragma unroll
    for (int c = 0; c < 8; ++c){
        int flat = c*1024 + t*4;
        int l = flat >> 7, k = flat & 127;
        *(float4*)&s_seq[l][k] = *(const float4*)(seq + (size_t)(bl*64 + l)*128 + k);
        *(float4*)&s_q2[l][k]  = *(const float4*)(q2m + (size_t)(bl*64 + l)*128 + k);
    }
    __syncthreads();
    {
        int l = t >> 2, gq = t & 3;
        float p = 0.f;
        #pragma unroll 8
        for (int hh = 0; hh < 32; ++hh){
            int h = gq*32 + hh;
            float sv = sigmoidf_(s_q1[h] + s_q2[l][h]);
            p += sv * W3[h];
        }
        s_part[l][gq] = p;
    }
    __syncthreads();
    if (t < 64){
        float al = s_part[t][0] + s_part[t][1] + s_part[t][2] + s_part[t][3];
        s_alpha[t] = (s_alias2[t] > 0) ? al : 0.f;
    }
    __syncthreads();
    if (t < 128){
        float a_ = 0.f;
        #pragma unroll 8
        for (int l = 0; l < 64; ++l) a_ += s_alpha[l]*s_seq[l][t];
        s_a[t] = a_;
    }
    __syncthreads();
    if (t < 128){
        int h = t;
        float o = bt[h];
        const float* wr = Wt + (size_t)h*256;
        #pragma unroll 8
        for (int k = 0; k < 128; ++k) o += s_a[k]*wr[k];
        #pragma unroll 8
        for (int k = 0; k < 128; ++k) o += s_ht[k]*wr[128+k];
        afin[(size_t)b*128 + h] = o;
    }
}

// ---------------- prep: afin f32 -> bf16 hi/lo A-fragments ----------------
__global__ __launch_bounds__(256) void k_prep_pred(
    const float* __restrict__ afin, unsigned short* __restrict__ Ahi,
    unsigned short* __restrict__ Alo)
{
    int idx = blockIdx.x*256 + threadIdx.x;
    int lane = idx & 63;
    int tile = idx >> 6;
    int mt = tile >> 2, ks = tile & 3;
    int row = mt*16 + (lane & 15);
    int k0  = ks*32 + (lane >> 4)*8;
    const float* src = afin + (size_t)row*128 + k0;
    float4 f0 = *(const float4*)(src);
    float4 f1 = *(const float4*)(src + 4);
    float xs[8] = {f0.x,f0.y,f0.z,f0.w,f1.x,f1.y,f1.z,f1.w};
    short8v h,l; split8(xs,h,l);
    *(short8v*)(Ahi + (size_t)idx*8) = h;
    *(short8v*)(Alo + (size_t)idx*8) = l;
}

// ---------------- pred = 16 * afin @ emb[1:]^T (2-product split, frag emb) ----------------
__global__ __launch_bounds__(256) void k_pred_mfma(
    const unsigned short* __restrict__ Ahi, const unsigned short* __restrict__ Alo,
    const unsigned short* __restrict__ Ebf, float* __restrict__ outp)
{
    const int t=threadIdx.x, lane=t&63, w=t>>6;
    const int vt=blockIdx.x, cb=vt*64;
    const int c15=lane&15, g=lane>>4;

    __shared__ float s_out[4][16][68];

    short8v B[16];
    #pragma unroll
    for (int q=0;q<16;++q){
        size_t off = (((size_t)vt*16 + q)*64 + lane)*8;
        B[q] = *(const short8v*)(Ebf + off);
    }

    for (int mt=w; mt<32; mt+=4){
        short8v ahi[4], alo[4];
        #pragma unroll
        for (int ks=0;ks<4;++ks){
            size_t off=((size_t)(mt*4+ks)*64+lane)*8;
            ahi[ks]=*(const short8v*)(Ahi+off);
            alo[ks]=*(const short8v*)(Alo+off);
        }
        #pragma unroll
        for (int nt=0;nt<4;++nt){
            f32x4 acc={0.f,0.f,0.f,0.f};
            #pragma unroll
            for (int ks=0;ks<4;++ks){
                acc=__builtin_amdgcn_mfma_f32_16x16x32_bf16(ahi[ks],B[nt*4+ks],acc,0,0,0);
                acc=__builtin_amdgcn_mfma_f32_16x16x32_bf16(alo[ks],B[nt*4+ks],acc,0,0,0);
            }
            #pragma unroll
            for (int j=0;j<4;++j) s_out[w][g*4+j][nt*16+c15] = 16.0f*acc[j];
        }
        // coalesced store of the 16x64 tile
        #pragma unroll
        for (int rep=0;rep<4;++rep){
            int f4 = rep*64 + lane;
            int r = f4 >> 4, c4 = (f4 & 15)*4;
            float4 o = *(float4*)&s_out[w][r][c4];
            int col = cb + c4;
            size_t rowoff = (size_t)(mt*16 + r)*NVOCAB;
            if (col + 3 < NVOCAB){
                *(float4*)(outp + rowoff + col) = o;
            } else {
                float vals[4]={o.x,o.y,o.z,o.w};
                #pragma unroll
                for (int cc=0;cc<4;++cc)
                    if (col+cc < NVOCAB) outp[rowoff + col + cc] = vals[cc];
            }
        }
    }
}

extern "C" void kernel_launch(void* const* d_in, const int* in_sizes, int n_in,
                              void* d_out, int out_size, void* d_ws, size_t ws_size,
                              hipStream_t stream)
{
    const int*   items = (const int*)  d_in[0];
    const float* Amat  = (const float*)d_in[1];
    const int*   alias = (const int*)  d_in[2];
    const float* emb   = (const float*)d_in[3];
    const float* pos   = (const float*)d_in[4];
    const float* lp    = (const float*)d_in[5];
    const float* w_ih  = (const float*)d_in[6];
    const float* w_hh  = (const float*)d_in[7];
    const float* b_ih  = (const float*)d_in[8];
    const float* b_hh  = (const float*)d_in[9];
    const float* b_iah = (const float*)d_in[10];
    const float* b_oah = (const float*)d_in[11];
    const float* W_in  = (const float*)d_in[12];
    const float* b_in  = (const float*)d_in[13];
    const float* W_out = (const float*)d_in[14];
    const float* b_out = (const float*)d_in[15];
    const float* W1    = (const float*)d_in[16];
    const float* b1    = (const float*)d_in[17];
    const float* W2    = (const float*)d_in[18];
    const float* b2    = (const float*)d_in[19];
    const float* W3    = (const float*)d_in[20];
    const float* Wt    = (const float*)d_in[21];
    const float* bt    = (const float*)d_in[22];
    float* outp = (float*)d_out;

    // ---- workspace carve ----
    float* wsf = (float*)d_ws;
    float* W2T    = wsf;                   size_t o = 16384;
    float* htb    = wsf + o;               o += 65536;
    float* q1b    = wsf + o;               o += 65536;
    float* afin   = wsf + o;               o += 65536;
    float* hidden = wsf + o;               o += 4194304;
    float* hidnew = wsf + o;               o += 4194304;
    float* seqb   = wsf + o;               o += 4194304;
    float* q2b    = wsf + o;               o += 4194304;
    unsigned short* us = (unsigned short*)(wsf + o);
    size_t uo = 0;
    unsigned short* wo_hi  = us + uo; uo += 32768;
    unsigned short* wo_lo  = us + uo; uo += 32768;
    unsigned short* wih_hi = us + uo; uo += 98304;
    unsigned short* wih_lo = us + uo; uo += 98304;
    unsigned short* whh_hi = us + uo; uo += 49152;
    unsigned short* whh_lo = us + uo; uo += 49152;
    unsigned short* pA_hi  = us + uo; uo += 65536;
    unsigned short* pA_lo  = us + uo; uo += 65536;
    unsigned short* hidf_hi= us + uo; uo += 4194304;
    unsigned short* hidf_lo= us + uo; uo += 4194304;
    unsigned short* inpf_hi= us + uo; uo += 8388608;
    unsigned short* inpf_lo= us + uo; uo += 8388608;
    unsigned short* Ebf    = us + uo; uo += 12804096;   // 1563*16*512

    ktrans<<<64, 256, 0, stream>>>(W2, W2T, 128, 128);
    k_prep_wfrag<<<88, 256, 0, stream>>>(W_in, W_out, w_ih, w_hh,
                                         wo_hi, wo_lo, wih_hi, wih_lo, whh_hi, whh_lo);
    k_prep_embf<<<6252, 256, 0, stream>>>(emb, Ebf);
    k_gnn1<<<512, 256, 0, stream>>>(items, Amat, emb, b_in, b_out, b_iah, b_oah,
                                    wo_hi, wo_lo, hidden, hidf_hi, hidf_lo, inpf_hi, inpf_lo);
    k_gru<<<512, 512, 0, stream>>>(inpf_hi, inpf_lo, hidf_hi, hidf_lo,
                                   wih_hi, wih_lo, whh_hi, whh_lo, b_ih, b_hh, hidden, hidnew);
    k_seq<<<512, 256, 0, stream>>>(alias, pos, lp, hidnew, W1, b1, seqb, htb, q1b, 0);
    k_gemm<<<dim3(1, 512), 256, 0, stream>>>(seqb, W2T, b2, q2b, 32768, 128, 128);
    k_attn<<<512, 256, 0, stream>>>(alias, seqb, q2b, q1b, htb, W3, Wt, bt, afin, 0);
    k_prep_pred<<<32, 256, 0, stream>>>(afin, pA_hi, pA_lo);
    k_pred_mfma<<<1563, 256, 0, stream>>>(pA_hi, pA_lo, Ebf, outp);
}

// Round 5
// 299.972 us; speedup vs baseline: 2.6305x; 1.3132x over previous
//
#include <hip/hip_runtime.h>
#include <cstddef>
#include <cstdint>

#define NVOCAB 99999

typedef __attribute__((ext_vector_type(8))) short short8v;
typedef __attribute__((ext_vector_type(4))) short short4v;
typedef __attribute__((ext_vector_type(4))) float f32x4;

__device__ __forceinline__ float sigmoidf_(float x){ return 1.0f/(1.0f + __expf(-x)); }

__device__ __forceinline__ unsigned short bf16rn(float x){
    union { float f; uint32_t u; } v; v.f = x;
    uint32_t r = v.u + 0x7FFFu + ((v.u >> 16) & 1u);
    return (unsigned short)(r >> 16);
}

__device__ __forceinline__ void split_bf16(float x, unsigned short &hi, unsigned short &lo){
    hi = bf16rn(x);
    union { uint32_t u; float f; } hf; hf.u = ((uint32_t)hi) << 16;
    lo = bf16rn(x - hf.f);
}

__device__ __forceinline__ void split8(const float* xs, short8v &h, short8v &l){
    #pragma unroll
    for (int e = 0; e < 8; ++e){
        unsigned short uh, ul;
        split_bf16(xs[e], uh, ul);
        h[e] = (short)uh; l[e] = (short)ul;
    }
}

// ---------------- generic transpose (tiny weights only) ----------------
__global__ void ktrans(const float* __restrict__ src, float* __restrict__ dst, int R, int C)
{
    int idx = blockIdx.x*256 + threadIdx.x;
    if (idx < R*C){ int r = idx / C; int c = idx - r*C; dst[c*R + r] = src[idx]; }
}

// ---------------- prep: split weights into B-fragment layout ----------------
__global__ __launch_bounds__(256) void k_prep_wfrag(
    const float* __restrict__ W_in, const float* __restrict__ W_out,
    const float* __restrict__ w_ih, const float* __restrict__ w_hh,
    unsigned short* __restrict__ wo_hi, unsigned short* __restrict__ wo_lo,
    unsigned short* __restrict__ wih_hi, unsigned short* __restrict__ wih_lo,
    unsigned short* __restrict__ whh_hi, unsigned short* __restrict__ whh_lo)
{
    int id = blockIdx.x*256 + threadIdx.x;
    const float* src; unsigned short *dh, *dl;
    if (id < 4096){
        int lane=id&63, tile=id>>6, nt=tile>>2, ks=tile&3;
        int col=nt*16+(lane&15), k=ks*32+(lane>>4)*8;
        src = (col<128) ? (W_in + (size_t)col*128 + k) : (W_out + (size_t)(col-128)*128 + k);
        dh=wo_hi+(size_t)id*8; dl=wo_lo+(size_t)id*8;
    } else if (id < 16384){
        int t2=id-4096, lane=t2&63, tile=t2>>6, nt=tile>>3, ks=tile&7;
        int col=nt*16+(lane&15), k=ks*32+(lane>>4)*8;
        src = w_ih + (size_t)col*256 + k;
        dh=wih_hi+(size_t)t2*8; dl=wih_lo+(size_t)t2*8;
    } else if (id < 22528){
        int t3=id-16384, lane=t3&63, tile=t3>>6, nt=tile>>2, ks=tile&3;
        int col=nt*16+(lane&15), k=ks*32+(lane>>4)*8;
        src = w_hh + (size_t)col*128 + k;
        dh=whh_hi+(size_t)t3*8; dl=whh_lo+(size_t)t3*8;
    } else return;
    float4 f0=*(const float4*)src, f1=*(const float4*)(src+4);
    float xs[8]={f0.x,f0.y,f0.z,f0.w,f1.x,f1.y,f1.z,f1.w};
    short8v h,l; split8(xs,h,l);
    *(short8v*)dh = h; *(short8v*)dl = l;
}

// ---------------- prep: emb -> bf16 B-fragments (hi only) ----------------
__global__ __launch_bounds__(256) void k_prep_embf(
    const float* __restrict__ emb, unsigned short* __restrict__ Ebf)
{
    int idx = blockIdx.x*256 + threadIdx.x;
    int v = idx >> 4;
    if (v >= 100032) return;
    int o = idx & 15;
    int srcr = (v < NVOCAB) ? (v+1) : 0;
    const float* src = emb + (size_t)srcr*128 + o*8;
    float4 f0=*(const float4*)src, f1=*(const float4*)(src+4);
    float xs[8]={f0.x,f0.y,f0.z,f0.w,f1.x,f1.y,f1.z,f1.w};
    short8v h;
    #pragma unroll
    for (int e=0;e<8;++e) h[e]=(short)bf16rn(xs[e]);
    int vt=v>>6, c=v&63, nt=c>>4, c15=c&15, ks=o>>2, gq=o&3;
    int lanez = gq*16 + c15;
    size_t off = (((size_t)vt*16 + nt*4 + ks)*64 + lanez)*8;
    *(short8v*)(Ebf + off) = h;
}

// ---------------- K1: gather + hv GEMM + bmm, emit hidden f32 + A-frag splits ----------------
union SharedU {
    struct { unsigned short hi[256][72]; unsigned short lo[256][72]; } hvT;
    float inp[64][268];
};

__global__ __launch_bounds__(256) void k_gnn1(
    const int* __restrict__ items, const float* __restrict__ Amat,
    const float* __restrict__ emb,
    const float* __restrict__ b_in, const float* __restrict__ b_out,
    const float* __restrict__ b_iah, const float* __restrict__ b_oah,
    const unsigned short* __restrict__ wo_hi, const unsigned short* __restrict__ wo_lo,
    float* __restrict__ hidden,
    unsigned short* __restrict__ hid_hi, unsigned short* __restrict__ hid_lo,
    unsigned short* __restrict__ inp_hi, unsigned short* __restrict__ inp_lo)
{
    const int t=threadIdx.x, lane=t&63, w=t>>6, bl=blockIdx.x;
    const int c15=lane&15, g=lane>>4, kg=g*8;
    const int mt=w;
    const int row=mt*16+c15;

    __shared__ int s_items[64];
    __shared__ SharedU U;

    if (t < 64) s_items[t]=items[bl*64+t];
    __syncthreads();

    short8v hhi[4], hlo[4];
    {
        const float* src = emb + (size_t)s_items[row]*128;
        float* hd = hidden + (size_t)(bl*64+row)*128;
        #pragma unroll
        for (int ks=0; ks<4; ++ks){
            float4 f0=*(const float4*)(src+ks*32+kg);
            float4 f1=*(const float4*)(src+ks*32+kg+4);
            *(float4*)(hd+ks*32+kg)=f0; *(float4*)(hd+ks*32+kg+4)=f1;
            float xs[8]={f0.x,f0.y,f0.z,f0.w,f1.x,f1.y,f1.z,f1.w};
            short8v h,l; split8(xs,h,l);
            hhi[ks]=h; hlo[ks]=l;
            size_t off=((size_t)(bl*4+mt)*4+ks)*512 + lane*8;
            *(short8v*)(hid_hi+off)=h; *(short8v*)(hid_lo+off)=l;
        }
    }

    f32x4 acc[16];
    #pragma unroll
    for (int nt=0;nt<16;++nt){
        int col=nt*16+c15;
        float bv=(col<128)? b_in[col] : b_out[col-128];
        acc[nt]=(f32x4){bv,bv,bv,bv};
    }
    #pragma unroll
    for (int ks=0; ks<4; ++ks){
        #pragma unroll
        for (int nt=0; nt<16; ++nt){
            size_t wo=((size_t)(nt*4+ks)*64+lane)*8;
            short8v bh=*(const short8v*)(wo_hi+wo);
            short8v bl_=*(const short8v*)(wo_lo+wo);
            acc[nt]=__builtin_amdgcn_mfma_f32_16x16x32_bf16(hhi[ks],bh,acc[nt],0,0,0);
            acc[nt]=__builtin_amdgcn_mfma_f32_16x16x32_bf16(hlo[ks],bh,acc[nt],0,0,0);
            acc[nt]=__builtin_amdgcn_mfma_f32_16x16x32_bf16(hhi[ks],bl_,acc[nt],0,0,0);
        }
    }

    {
        const int r0=g*4;
        #pragma unroll
        for (int nt=0;nt<16;++nt){
            int col=nt*16+c15;
            short4v h4,l4;
            #pragma unroll
            for (int j=0;j<4;++j){
                unsigned short uh,ul; split_bf16(acc[nt][j],uh,ul);
                h4[j]=(short)uh; l4[j]=(short)ul;
            }
            *(short4v*)&U.hvT.hi[col][mt*16+r0] = h4;
            *(short4v*)&U.hvT.lo[col][mt*16+r0] = l4;
        }
    }
    __syncthreads();

    f32x4 acc2[16];
    #pragma unroll
    for (int nt=0;nt<16;++nt){
        int col=nt*16+c15;
        float bv=(col<128)? b_iah[col] : b_oah[col-128];
        acc2[nt]=(f32x4){bv,bv,bv,bv};
    }
    short8v aihi[2],ailo[2],aohi[2],aolo[2];
    {
        const float* Ab = Amat + (size_t)bl*8192 + (size_t)row*128;
        #pragma unroll
        for (int ks=0;ks<2;++ks){
            float4 f0=*(const float4*)(Ab+ks*32+kg);
            float4 f1=*(const float4*)(Ab+ks*32+kg+4);
            float xs[8]={f0.x,f0.y,f0.z,f0.w,f1.x,f1.y,f1.z,f1.w};
            split8(xs,aihi[ks],ailo[ks]);
            float4 g0=*(const float4*)(Ab+64+ks*32+kg);
            float4 g1=*(const float4*)(Ab+64+ks*32+kg+4);
            float ys[8]={g0.x,g0.y,g0.z,g0.w,g1.x,g1.y,g1.z,g1.w};
            split8(ys,aohi[ks],aolo[ks]);
        }
    }
    #pragma unroll
    for (int ks=0;ks<2;++ks){
        #pragma unroll
        for (int nt=0;nt<16;++nt){
            int h=nt*16+c15;
            int m0=ks*32+kg;
            short8v bh=*(const short8v*)&U.hvT.hi[h][m0];
            short8v bl_=*(const short8v*)&U.hvT.lo[h][m0];
            short8v ah=(nt<8)?aihi[ks]:aohi[ks];
            short8v al=(nt<8)?ailo[ks]:aolo[ks];
            acc2[nt]=__builtin_amdgcn_mfma_f32_16x16x32_bf16(ah,bh,acc2[nt],0,0,0);
            acc2[nt]=__builtin_amdgcn_mfma_f32_16x16x32_bf16(al,bh,acc2[nt],0,0,0);
            acc2[nt]=__builtin_amdgcn_mfma_f32_16x16x32_bf16(ah,bl_,acc2[nt],0,0,0);
        }
    }
    __syncthreads();

    {
        #pragma unroll
        for (int nt=0;nt<16;++nt){
            int col=nt*16+c15;
            #pragma unroll
            for (int j=0;j<4;++j)
                U.inp[mt*16+g*4+j][col]=acc2[nt][j];
        }
    }
    __syncthreads();

    {
        #pragma unroll
        for (int ks=0;ks<8;++ks){
            float4 f0=*(const float4*)&U.inp[row][ks*32+kg];
            float4 f1=*(const float4*)&U.inp[row][ks*32+kg+4];
            float xs[8]={f0.x,f0.y,f0.z,f0.w,f1.x,f1.y,f1.z,f1.w};
            short8v h,l; split8(xs,h,l);
            size_t off=((size_t)(bl*4+mt)*8+ks)*512 + lane*8;
            *(short8v*)(inp_hi+off)=h; *(short8v*)(inp_lo+off)=l;
        }
    }
}

// ---------------- K2: gi/gh GEMMs + GRU gate (2 waves per row-tile) ----------------
__global__ __launch_bounds__(512,1) void k_gru(
    const unsigned short* __restrict__ inp_hi, const unsigned short* __restrict__ inp_lo,
    const unsigned short* __restrict__ hid_hi, const unsigned short* __restrict__ hid_lo,
    const unsigned short* __restrict__ wih_hi, const unsigned short* __restrict__ wih_lo,
    const unsigned short* __restrict__ whh_hi, const unsigned short* __restrict__ whh_lo,
    const float* __restrict__ b_ih, const float* __restrict__ b_hh,
    const float* __restrict__ hidden, float* __restrict__ hidnew)
{
    const int t=threadIdx.x, lane=t&63, w=t>>6;
    const int wh = w & 1;
    const int gmt = blockIdx.x*4 + (w>>1);
    const int c15=lane&15, g=lane>>4;

    __shared__ unsigned short wbuf[2][24][1024];

    auto stage=[&](int ks, int buf){
        #pragma unroll
        for (int i=0;i<3;++i){
            int idx=i*512+t;
            int nt=idx>>6, ln=idx&63;
            const unsigned short *sh, *sl;
            if (ks<4){ size_t o=((size_t)(nt*4+ks)*64+ln)*8; sh=whh_hi+o; sl=whh_lo+o; }
            else     { size_t o=((size_t)(nt*8+(ks-4))*64+ln)*8; sh=wih_hi+o; sl=wih_lo+o; }
            *(short8v*)&wbuf[buf][nt][ln*8]     = *(const short8v*)sh;
            *(short8v*)&wbuf[buf][nt][512+ln*8] = *(const short8v*)sl;
        }
    };

    f32x4 agi[12], agh[12];
    #pragma unroll
    for (int j=0;j<12;++j){
        int nt=(j>>2)*8 + wh*4 + (j&3);
        int col=nt*16+c15;
        float bi=b_ih[col], bh=b_hh[col];
        agi[j]=(f32x4){bi,bi,bi,bi};
        agh[j]=(f32x4){bh,bh,bh,bh};
    }

    stage(0,0);
    __syncthreads();
    for (int ks=0; ks<12; ++ks){
        int buf=ks&1;
        if (ks<11) stage(ks+1, buf^1);
        short8v ah, al;
        if (ks<4){
            size_t o=((size_t)gmt*4+ks)*512 + (size_t)lane*8;
            ah=*(const short8v*)(hid_hi+o); al=*(const short8v*)(hid_lo+o);
        } else {
            size_t o=((size_t)gmt*8+(ks-4))*512 + (size_t)lane*8;
            ah=*(const short8v*)(inp_hi+o); al=*(const short8v*)(inp_lo+o);
        }
        if (ks<4){
            #pragma unroll
            for (int j=0;j<12;++j){
                int nt=(j>>2)*8 + wh*4 + (j&3);
                short8v bh=*(const short8v*)&wbuf[buf][nt][lane*8];
                short8v bl_=*(const short8v*)&wbuf[buf][nt][512+lane*8];
                agh[j]=__builtin_amdgcn_mfma_f32_16x16x32_bf16(ah,bh,agh[j],0,0,0);
                agh[j]=__builtin_amdgcn_mfma_f32_16x16x32_bf16(al,bh,agh[j],0,0,0);
                agh[j]=__builtin_amdgcn_mfma_f32_16x16x32_bf16(ah,bl_,agh[j],0,0,0);
            }
        } else {
            #pragma unroll
            for (int j=0;j<12;++j){
                int nt=(j>>2)*8 + wh*4 + (j&3);
                short8v bh=*(const short8v*)&wbuf[buf][nt][lane*8];
                short8v bl_=*(const short8v*)&wbuf[buf][nt][512+lane*8];
                agi[j]=__builtin_amdgcn_mfma_f32_16x16x32_bf16(ah,bh,agi[j],0,0,0);
                agi[j]=__builtin_amdgcn_mfma_f32_16x16x32_bf16(al,bh,agi[j],0,0,0);
                agi[j]=__builtin_amdgcn_mfma_f32_16x16x32_bf16(ah,bl_,agi[j],0,0,0);
            }
        }
        __syncthreads();
    }

    const int r0=gmt*16+g*4;
    #pragma unroll
    for (int sub=0;sub<4;++sub){
        int h=(wh*4+sub)*16+c15;
        #pragma unroll
        for (int j2=0;j2<4;++j2){
            float ir=agi[sub][j2], ii=agi[4+sub][j2], in_=agi[8+sub][j2];
            float hr=agh[sub][j2], hi_=agh[4+sub][j2], hn=agh[8+sub][j2];
            float rg=sigmoidf_(ir+hr), ig=sigmoidf_(ii+hi_);
            float ng=tanhf(in_+rg*hn);
            float ho=hidden[(size_t)(r0+j2)*128+h];
            hidnew[(size_t)(r0+j2)*128+h]=ng+ig*(ho-ng);
        }
    }
}

// ---------------- generic fp32 GEMM (kept for q2) ----------------
__global__ __launch_bounds__(256) void k_gemm(
    const float* __restrict__ A, const float* __restrict__ Bt,
    const float* __restrict__ bias, float* __restrict__ C,
    int M, int N, int K)
{
    const int t = threadIdx.x;
    const int tc = t & 31, tr = t >> 5;
    const int rb = blockIdx.y * 64;
    const int cb = blockIdx.x * 128;

    __shared__ float As[64][36];
    __shared__ float Ws[32][132];

    float acc[8][4];
    {
        float4 bv = *(const float4*)(bias + cb + tc*4);
        #pragma unroll
        for (int i = 0; i < 8; ++i){ acc[i][0]=bv.x; acc[i][1]=bv.y; acc[i][2]=bv.z; acc[i][3]=bv.w; }
    }

    for (int kc = 0; kc < K; kc += 32){
        int arow = t >> 2;
        int ak0  = (t & 3) * 8;
        const float* asrc = A + (size_t)(rb + arow)*K + kc + ak0;
        float4 av0 = *(const float4*)(asrc);
        float4 av1 = *(const float4*)(asrc + 4);
        int wk  = t >> 3;
        int wc0 = (t & 7) * 16;
        const float* wsrc = Bt + (size_t)(kc + wk)*N + cb + wc0;
        float4 wv0 = *(const float4*)(wsrc);
        float4 wv1 = *(const float4*)(wsrc + 4);
        float4 wv2 = *(const float4*)(wsrc + 8);
        float4 wv3 = *(const float4*)(wsrc + 12);
        __syncthreads();
        *(float4*)&As[arow][ak0]   = av0;
        *(float4*)&As[arow][ak0+4] = av1;
        *(float4*)&Ws[wk][wc0]     = wv0;
        *(float4*)&Ws[wk][wc0+4]   = wv1;
        *(float4*)&Ws[wk][wc0+8]   = wv2;
        *(float4*)&Ws[wk][wc0+12]  = wv3;
        __syncthreads();
        #pragma unroll
        for (int k = 0; k < 32; ++k){
            float4 wv = *(const float4*)&Ws[k][tc*4];
            #pragma unroll
            for (int i = 0; i < 8; ++i){
                float a_ = As[tr*8+i][k];
                acc[i][0] += a_*wv.x; acc[i][1] += a_*wv.y;
                acc[i][2] += a_*wv.z; acc[i][3] += a_*wv.w;
            }
        }
    }
    #pragma unroll
    for (int i = 0; i < 8; ++i){
        float4 o; o.x=acc[i][0]; o.y=acc[i][1]; o.z=acc[i][2]; o.w=acc[i][3];
        *(float4*)(C + (size_t)(rb + tr*8 + i)*N + cb + tc*4) = o;
    }
}

// ---------------- seq ----------------
__global__ __launch_bounds__(256) void k_seq(
    const int* __restrict__ alias, const float* __restrict__ pos,
    const float* __restrict__ lp, const float* __restrict__ hn,
    const float* __restrict__ W1, const float* __restrict__ b1,
    float* __restrict__ seq, float* __restrict__ ht, float* __restrict__ q1,
    int b0)
{
    const int t = threadIdx.x;
    const int bl = blockIdx.x, b = b0 + bl;
    __shared__ float Xs[64][260];
    __shared__ float Ys[64][132];
    __shared__ int s_alias[64];
    __shared__ float s_rn[64];
    __shared__ int s_last;

    if (t < 64) s_alias[t] = alias[b*64 + t];
    __syncthreads();
    if (t == 0){
        int cnt = 0;
        for (int l = 0; l < 64; ++l) cnt += (s_alias[l] > 0) ? 1 : 0;
        s_last = (cnt - 1) & 63;
    }
    #pragma unroll
    for (int c = 0; c < 8; ++c){
        int flat = c*1024 + t*4;
        int l = flat >> 7, k = flat & 127;
        *(float4*)&Xs[l][k] = *(const float4*)(pos + l*128 + k);
        int row = s_alias[l];
        *(float4*)&Xs[l][128+k] = *(const float4*)(hn + (size_t)(bl*64 + row)*128 + k);
    }
    __syncthreads();

    const int tc = t & 31, tr = t >> 5;
    float acc[8][4];
    #pragma unroll
    for (int i=0;i<8;i++){ acc[i][0]=0.f; acc[i][1]=0.f; acc[i][2]=0.f; acc[i][3]=0.f; }

    for (int k = 0; k < 256; k += 4){
        float4 w0 = *(const float4*)(lp + (size_t)(k+0)*128 + tc*4);
        float4 w1 = *(const float4*)(lp + (size_t)(k+1)*128 + tc*4);
        float4 w2 = *(const float4*)(lp + (size_t)(k+2)*128 + tc*4);
        float4 w3 = *(const float4*)(lp + (size_t)(k+3)*128 + tc*4);
        #pragma unroll
        for (int i = 0; i < 8; ++i){
            float4 a4 = *(const float4*)&Xs[tr*8+i][k];
            acc[i][0] += a4.x*w0.x + a4.y*w1.x + a4.z*w2.x + a4.w*w3.x;
            acc[i][1] += a4.x*w0.y + a4.y*w1.y + a4.z*w2.y + a4.w*w3.y;
            acc[i][2] += a4.x*w0.z + a4.y*w1.z + a4.z*w2.z + a4.w*w3.z;
            acc[i][3] += a4.x*w0.w + a4.y*w1.w + a4.z*w2.w + a4.w*w3.w;
        }
    }
    #pragma unroll
    for (int i = 0; i < 8; ++i){
        float4 o;
        o.x = tanhf(acc[i][0]); o.y = tanhf(acc[i][1]);
        o.z = tanhf(acc[i][2]); o.w = tanhf(acc[i][3]);
        *(float4*)&Ys[tr*8+i][tc*4] = o;
    }
    __syncthreads();
    if (t < 64){
        float s = 0.f;
        #pragma unroll 8
        for (int k = 0; k < 128; ++k){ float v = Ys[t][k]; s = fmaf(v, v, s); }
        s_rn[t] = rsqrtf(s);
    }
    __syncthreads();
    #pragma unroll
    for (int c = 0; c < 8; ++c){
        int flat = c*1024 + t*4;
        int l = flat >> 7, k = flat & 127;
        float rn = s_rn[l];
        float4 o;
        o.x = Ys[l][k+0]*rn; o.y = Ys[l][k+1]*rn; o.z = Ys[l][k+2]*rn; o.w = Ys[l][k+3]*rn;
        *(float4*)(seq + (size_t)(bl*64 + l)*128 + k) = o;
    }
    if (t < 128){
        int h = t;
        int lst = s_last;
        float rn = s_rn[lst];
        float hv = Ys[lst][h]*rn;
        ht[(size_t)b*128 + h] = hv;
        float o = b1[h];
        const float* wr = W1 + (size_t)h*128;
        #pragma unroll 8
        for (int k = 0; k < 128; ++k) o += (Ys[lst][k]*rn) * wr[k];
        q1[(size_t)b*128 + h] = o;
    }
}

// ---------------- attention + final projection ----------------
__global__ __launch_bounds__(256) void k_attn(
    const int* __restrict__ alias, const float* __restrict__ seq,
    const float* __restrict__ q2m, const float* __restrict__ q1,
    const float* __restrict__ ht, const float* __restrict__ W3,
    const float* __restrict__ Wt, const float* __restrict__ bt,
    float* __restrict__ afin, int b0)
{
    const int t = threadIdx.x;
    const int bl = blockIdx.x, b = b0 + bl;
    __shared__ float s_seq[64][132];
    __shared__ float s_q2[64][132];
    __shared__ float s_q1[128], s_ht[128];
    __shared__ float s_part[64][4];
    __shared__ float s_alpha[64];
    __shared__ float s_a[128];
    __shared__ int s_alias2[64];

    if (t < 64) s_alias2[t] = alias[b*64 + t];
    if (t < 128){ s_q1[t] = q1[(size_t)b*128 + t]; s_ht[t] = ht[(size_t)b*128 + t]; }
    #pragma unroll
    for (int c = 0; c < 8; ++c){
        int flat = c*1024 + t*4;
        int l = flat >> 7, k = flat & 127;
        *(float4*)&s_seq[l][k] = *(const float4*)(seq + (size_t)(bl*64 + l)*128 + k);
        *(float4*)&s_q2[l][k]  = *(const float4*)(q2m + (size_t)(bl*64 + l)*128 + k);
    }
    __syncthreads();
    {
        int l = t >> 2, gq = t & 3;
        float p = 0.f;
        #pragma unroll 8
        for (int hh = 0; hh < 32; ++hh){
            int h = gq*32 + hh;
            float sv = sigmoidf_(s_q1[h] + s_q2[l][h]);
            p += sv * W3[h];
        }
        s_part[l][gq] = p;
    }
    __syncthreads();
    if (t < 64){
        float al = s_part[t][0] + s_part[t][1] + s_part[t][2] + s_part[t][3];
        s_alpha[t] = (s_alias2[t] > 0) ? al : 0.f;
    }
    __syncthreads();
    if (t < 128){
        float a_ = 0.f;
        #pragma unroll 8
        for (int l = 0; l < 64; ++l) a_ += s_alpha[l]*s_seq[l][t];
        s_a[t] = a_;
    }
    __syncthreads();
    if (t < 128){
        int h = t;
        float o = bt[h];
        const float* wr = Wt + (size_t)h*256;
        #pragma unroll 8
        for (int k = 0; k < 128; ++k) o += s_a[k]*wr[k];
        #pragma unroll 8
        for (int k = 0; k < 128; ++k) o += s_ht[k]*wr[128+k];
        afin[(size_t)b*128 + h] = o;
    }
}

// ---------------- prep: afin f32 -> bf16 hi/lo A-fragments ----------------
__global__ __launch_bounds__(256) void k_prep_pred(
    const float* __restrict__ afin, unsigned short* __restrict__ Ahi,
    unsigned short* __restrict__ Alo)
{
    int idx = blockIdx.x*256 + threadIdx.x;
    int lane = idx & 63;
    int tile = idx >> 6;
    int mt = tile >> 2, ks = tile & 3;
    int row = mt*16 + (lane & 15);
    int k0  = ks*32 + (lane >> 4)*8;
    const float* src = afin + (size_t)row*128 + k0;
    float4 f0 = *(const float4*)(src);
    float4 f1 = *(const float4*)(src + 4);
    float xs[8] = {f0.x,f0.y,f0.z,f0.w,f1.x,f1.y,f1.z,f1.w};
    short8v h,l; split8(xs,h,l);
    *(short8v*)(Ahi + (size_t)idx*8) = h;
    *(short8v*)(Alo + (size_t)idx*8) = l;
}

// ---------------- pred = 16 * afin @ emb[1:]^T (2-product split, frag emb) ----------------
__global__ __launch_bounds__(256) void k_pred_mfma(
    const unsigned short* __restrict__ Ahi, const unsigned short* __restrict__ Alo,
    const unsigned short* __restrict__ Ebf, float* __restrict__ outp)
{
    const int t=threadIdx.x, lane=t&63, w=t>>6;
    const int vt=blockIdx.x, cb=vt*64;
    const int c15=lane&15, g=lane>>4;

    __shared__ float s_out[4][16][68];

    short8v B[16];
    #pragma unroll
    for (int q=0;q<16;++q){
        size_t off = (((size_t)vt*16 + q)*64 + lane)*8;
        B[q] = *(const short8v*)(Ebf + off);
    }

    for (int mt=w; mt<32; mt+=4){
        short8v ahi[4], alo[4];
        #pragma unroll
        for (int ks=0;ks<4;++ks){
            size_t off=((size_t)(mt*4+ks)*64+lane)*8;
            ahi[ks]=*(const short8v*)(Ahi+off);
            alo[ks]=*(const short8v*)(Alo+off);
        }
        #pragma unroll
        for (int nt=0;nt<4;++nt){
            f32x4 acc={0.f,0.f,0.f,0.f};
            #pragma unroll
            for (int ks=0;ks<4;++ks){
                acc=__builtin_amdgcn_mfma_f32_16x16x32_bf16(ahi[ks],B[nt*4+ks],acc,0,0,0);
                acc=__builtin_amdgcn_mfma_f32_16x16x32_bf16(alo[ks],B[nt*4+ks],acc,0,0,0);
            }
            #pragma unroll
            for (int j=0;j<4;++j) s_out[w][g*4+j][nt*16+c15] = 16.0f*acc[j];
        }
        #pragma unroll
        for (int rep=0;rep<4;++rep){
            int f4 = rep*64 + lane;
            int r = f4 >> 4, c4 = (f4 & 15)*4;
            float4 o = *(float4*)&s_out[w][r][c4];
            int col = cb + c4;
            size_t rowoff = (size_t)(mt*16 + r)*NVOCAB;
            if (col + 3 < NVOCAB){
                *(float4*)(outp + rowoff + col) = o;
            } else {
                float vals[4]={o.x,o.y,o.z,o.w};
                #pragma unroll
                for (int cc=0;cc<4;++cc)
                    if (col+cc < NVOCAB) outp[rowoff + col + cc] = vals[cc];
            }
        }
    }
}

extern "C" void kernel_launch(void* const* d_in, const int* in_sizes, int n_in,
                              void* d_out, int out_size, void* d_ws, size_t ws_size,
                              hipStream_t stream)
{
    const int*   items = (const int*)  d_in[0];
    const float* Amat  = (const float*)d_in[1];
    const int*   alias = (const int*)  d_in[2];
    const float* emb   = (const float*)d_in[3];
    const float* pos   = (const float*)d_in[4];
    const float* lp    = (const float*)d_in[5];
    const float* w_ih  = (const float*)d_in[6];
    const float* w_hh  = (const float*)d_in[7];
    const float* b_ih  = (const float*)d_in[8];
    const float* b_hh  = (const float*)d_in[9];
    const float* b_iah = (const float*)d_in[10];
    const float* b_oah = (const float*)d_in[11];
    const float* W_in  = (const float*)d_in[12];
    const float* b_in  = (const float*)d_in[13];
    const float* W_out = (const float*)d_in[14];
    const float* b_out = (const float*)d_in[15];
    const float* W1    = (const float*)d_in[16];
    const float* b1    = (const float*)d_in[17];
    const float* W2    = (const float*)d_in[18];
    const float* b2    = (const float*)d_in[19];
    const float* W3    = (const float*)d_in[20];
    const float* Wt    = (const float*)d_in[21];
    const float* bt    = (const float*)d_in[22];
    float* outp = (float*)d_out;

    // ---- workspace carve ----
    float* wsf = (float*)d_ws;
    float* W2T    = wsf;                   size_t o = 16384;
    float* htb    = wsf + o;               o += 65536;
    float* q1b    = wsf + o;               o += 65536;
    float* afin   = wsf + o;               o += 65536;
    float* hidden = wsf + o;               o += 4194304;
    float* hidnew = wsf + o;               o += 4194304;
    float* seqb   = wsf + o;               o += 4194304;
    float* q2b    = wsf + o;               o += 4194304;
    unsigned short* us = (unsigned short*)(wsf + o);
    size_t uo = 0;
    unsigned short* wo_hi  = us + uo; uo += 32768;
    unsigned short* wo_lo  = us + uo; uo += 32768;
    unsigned short* wih_hi = us + uo; uo += 98304;
    unsigned short* wih_lo = us + uo; uo += 98304;
    unsigned short* whh_hi = us + uo; uo += 49152;
    unsigned short* whh_lo = us + uo; uo += 49152;
    unsigned short* pA_hi  = us + uo; uo += 65536;
    unsigned short* pA_lo  = us + uo; uo += 65536;
    unsigned short* hidf_hi= us + uo; uo += 4194304;
    unsigned short* hidf_lo= us + uo; uo += 4194304;
    unsigned short* inpf_hi= us + uo; uo += 8388608;
    unsigned short* inpf_lo= us + uo; uo += 8388608;
    unsigned short* Ebf    = us + uo; uo += 12804096;

    ktrans<<<64, 256, 0, stream>>>(W2, W2T, 128, 128);
    k_prep_wfrag<<<88, 256, 0, stream>>>(W_in, W_out, w_ih, w_hh,
                                         wo_hi, wo_lo, wih_hi, wih_lo, whh_hi, whh_lo);
    k_prep_embf<<<6252, 256, 0, stream>>>(emb, Ebf);
    k_gnn1<<<512, 256, 0, stream>>>(items, Amat, emb, b_in, b_out, b_iah, b_oah,
                                    wo_hi, wo_lo, hidden, hidf_hi, hidf_lo, inpf_hi, inpf_lo);
    k_gru<<<512, 512, 0, stream>>>(inpf_hi, inpf_lo, hidf_hi, hidf_lo,
                                   wih_hi, wih_lo, whh_hi, whh_lo, b_ih, b_hh, hidden, hidnew);
    k_seq<<<512, 256, 0, stream>>>(alias, pos, lp, hidnew, W1, b1, seqb, htb, q1b, 0);
    k_gemm<<<dim3(1, 512), 256, 0, stream>>>(seqb, W2T, b2, q2b, 32768, 128, 128);
    k_attn<<<512, 256, 0, stream>>>(alias, seqb, q2b, q1b, htb, W3, Wt, bt, afin, 0);
    k_prep_pred<<<32, 256, 0, stream>>>(afin, pA_hi, pA_lo);
    k_pred_mfma<<<1563, 256, 0, stream>>>(pA_hi, pA_lo, Ebf, outp);
}

// Round 6
// 241.900 us; speedup vs baseline: 3.2620x; 1.2401x over previous
//
#include <hip/hip_runtime.h>
#include <cstddef>
#include <cstdint>

#define NVOCAB 99999

typedef __attribute__((ext_vector_type(8))) short short8v;
typedef __attribute__((ext_vector_type(4))) short short4v;
typedef __attribute__((ext_vector_type(4))) float f32x4;

__device__ __forceinline__ float sigmoidf_(float x){ return 1.0f/(1.0f + __expf(-x)); }

__device__ __forceinline__ unsigned short bf16rn(float x){
    union { float f; uint32_t u; } v; v.f = x;
    uint32_t r = v.u + 0x7FFFu + ((v.u >> 16) & 1u);
    return (unsigned short)(r >> 16);
}

__device__ __forceinline__ void split_bf16(float x, unsigned short &hi, unsigned short &lo){
    hi = bf16rn(x);
    union { uint32_t u; float f; } hf; hf.u = ((uint32_t)hi) << 16;
    lo = bf16rn(x - hf.f);
}

__device__ __forceinline__ void split8(const float* xs, short8v &h, short8v &l){
    #pragma unroll
    for (int e = 0; e < 8; ++e){
        unsigned short uh, ul;
        split_bf16(xs[e], uh, ul);
        h[e] = (short)uh; l[e] = (short)ul;
    }
}

// ---------------- prep: split weights into B-fragment layout ----------------
// ids: [0,4096) wo | [4096,16384) wih | [16384,22528) whh | [22528,26624) lp | [26624,28672) W2
__global__ __launch_bounds__(256) void k_prep_wfrag(
    const float* __restrict__ W_in, const float* __restrict__ W_out,
    const float* __restrict__ w_ih, const float* __restrict__ w_hh,
    const float* __restrict__ lp,  const float* __restrict__ W2,
    unsigned short* __restrict__ wo_hi, unsigned short* __restrict__ wo_lo,
    unsigned short* __restrict__ wih_hi, unsigned short* __restrict__ wih_lo,
    unsigned short* __restrict__ whh_hi, unsigned short* __restrict__ whh_lo,
    unsigned short* __restrict__ lp_hi,  unsigned short* __restrict__ lp_lo,
    unsigned short* __restrict__ w2_hi,  unsigned short* __restrict__ w2_lo)
{
    int id = blockIdx.x*256 + threadIdx.x;
    const float* src; unsigned short *dh, *dl;
    if (id < 4096){
        int lane=id&63, tile=id>>6, nt=tile>>2, ks=tile&3;
        int col=nt*16+(lane&15), k=ks*32+(lane>>4)*8;
        src = (col<128) ? (W_in + (size_t)col*128 + k) : (W_out + (size_t)(col-128)*128 + k);
        dh=wo_hi+(size_t)id*8; dl=wo_lo+(size_t)id*8;
    } else if (id < 16384){
        int t2=id-4096, lane=t2&63, tile=t2>>6, nt=tile>>3, ks=tile&7;
        int col=nt*16+(lane&15), k=ks*32+(lane>>4)*8;
        src = w_ih + (size_t)col*256 + k;
        dh=wih_hi+(size_t)t2*8; dl=wih_lo+(size_t)t2*8;
    } else if (id < 22528){
        int t3=id-16384, lane=t3&63, tile=t3>>6, nt=tile>>2, ks=tile&3;
        int col=nt*16+(lane&15), k=ks*32+(lane>>4)*8;
        src = w_hh + (size_t)col*128 + k;
        dh=whh_hi+(size_t)t3*8; dl=whh_lo+(size_t)t3*8;
    } else if (id < 26624){
        // lp is [256][128] stored k-major: value = lp[k][col] (strided gather)
        int t4=id-22528, lane=t4&63, tile=t4>>6, nt=tile>>3, ks=tile&7;
        int col=nt*16+(lane&15), k=ks*32+(lane>>4)*8;
        float xs[8];
        #pragma unroll
        for (int e=0;e<8;++e) xs[e]=lp[(size_t)(k+e)*128 + col];
        short8v h,l; split8(xs,h,l);
        *(short8v*)(lp_hi+(size_t)t4*8)=h; *(short8v*)(lp_lo+(size_t)t4*8)=l;
        return;
    } else if (id < 28672){
        int t5=id-26624, lane=t5&63, tile=t5>>6, nt=tile>>2, ks=tile&3;
        int col=nt*16+(lane&15), k=ks*32+(lane>>4)*8;
        src = W2 + (size_t)col*128 + k;
        dh=w2_hi+(size_t)t5*8; dl=w2_lo+(size_t)t5*8;
    } else return;
    float4 f0=*(const float4*)src, f1=*(const float4*)(src+4);
    float xs[8]={f0.x,f0.y,f0.z,f0.w,f1.x,f1.y,f1.z,f1.w};
    short8v h,l; split8(xs,h,l);
    *(short8v*)dh = h; *(short8v*)dl = l;
}

// ---------------- prep: emb -> bf16 B-fragments (hi only) ----------------
__global__ __launch_bounds__(256) void k_prep_embf(
    const float* __restrict__ emb, unsigned short* __restrict__ Ebf)
{
    int idx = blockIdx.x*256 + threadIdx.x;
    int v = idx >> 4;
    if (v >= 100032) return;
    int o = idx & 15;
    int srcr = (v < NVOCAB) ? (v+1) : 0;
    const float* src = emb + (size_t)srcr*128 + o*8;
    float4 f0=*(const float4*)src, f1=*(const float4*)(src+4);
    float xs[8]={f0.x,f0.y,f0.z,f0.w,f1.x,f1.y,f1.z,f1.w};
    short8v h;
    #pragma unroll
    for (int e=0;e<8;++e) h[e]=(short)bf16rn(xs[e]);
    int vt=v>>6, c=v&63, nt=c>>4, c15=c&15, ks=o>>2, gq=o&3;
    int lanez = gq*16 + c15;
    size_t off = (((size_t)vt*16 + nt*4 + ks)*64 + lanez)*8;
    *(short8v*)(Ebf + off) = h;
}

// ---------------- K1: gather + hv GEMM + bmm, emit hidden f32 + A-frag splits ----------------
union SharedU {
    struct { unsigned short hi[256][72]; unsigned short lo[256][72]; } hvT;
    float inp[64][268];
};

__global__ __launch_bounds__(256) void k_gnn1(
    const int* __restrict__ items, const float* __restrict__ Amat,
    const float* __restrict__ emb,
    const float* __restrict__ b_in, const float* __restrict__ b_out,
    const float* __restrict__ b_iah, const float* __restrict__ b_oah,
    const unsigned short* __restrict__ wo_hi, const unsigned short* __restrict__ wo_lo,
    float* __restrict__ hidden,
    unsigned short* __restrict__ hid_hi, unsigned short* __restrict__ hid_lo,
    unsigned short* __restrict__ inp_hi, unsigned short* __restrict__ inp_lo)
{
    const int t=threadIdx.x, lane=t&63, w=t>>6, bl=blockIdx.x;
    const int c15=lane&15, g=lane>>4, kg=g*8;
    const int mt=w;
    const int row=mt*16+c15;

    __shared__ int s_items[64];
    __shared__ SharedU U;

    if (t < 64) s_items[t]=items[bl*64+t];
    __syncthreads();

    short8v hhi[4], hlo[4];
    {
        const float* src = emb + (size_t)s_items[row]*128;
        float* hd = hidden + (size_t)(bl*64+row)*128;
        #pragma unroll
        for (int ks=0; ks<4; ++ks){
            float4 f0=*(const float4*)(src+ks*32+kg);
            float4 f1=*(const float4*)(src+ks*32+kg+4);
            *(float4*)(hd+ks*32+kg)=f0; *(float4*)(hd+ks*32+kg+4)=f1;
            float xs[8]={f0.x,f0.y,f0.z,f0.w,f1.x,f1.y,f1.z,f1.w};
            short8v h,l; split8(xs,h,l);
            hhi[ks]=h; hlo[ks]=l;
            size_t off=((size_t)(bl*4+mt)*4+ks)*512 + lane*8;
            *(short8v*)(hid_hi+off)=h; *(short8v*)(hid_lo+off)=l;
        }
    }

    f32x4 acc[16];
    #pragma unroll
    for (int nt=0;nt<16;++nt){
        int col=nt*16+c15;
        float bv=(col<128)? b_in[col] : b_out[col-128];
        acc[nt]=(f32x4){bv,bv,bv,bv};
    }
    #pragma unroll
    for (int ks=0; ks<4; ++ks){
        #pragma unroll
        for (int nt=0; nt<16; ++nt){
            size_t wo=((size_t)(nt*4+ks)*64+lane)*8;
            short8v bh=*(const short8v*)(wo_hi+wo);
            short8v bl_=*(const short8v*)(wo_lo+wo);
            acc[nt]=__builtin_amdgcn_mfma_f32_16x16x32_bf16(hhi[ks],bh,acc[nt],0,0,0);
            acc[nt]=__builtin_amdgcn_mfma_f32_16x16x32_bf16(hlo[ks],bh,acc[nt],0,0,0);
            acc[nt]=__builtin_amdgcn_mfma_f32_16x16x32_bf16(hhi[ks],bl_,acc[nt],0,0,0);
        }
    }

    {
        const int r0=g*4;
        #pragma unroll
        for (int nt=0;nt<16;++nt){
            int col=nt*16+c15;
            short4v h4,l4;
            #pragma unroll
            for (int j=0;j<4;++j){
                unsigned short uh,ul; split_bf16(acc[nt][j],uh,ul);
                h4[j]=(short)uh; l4[j]=(short)ul;
            }
            *(short4v*)&U.hvT.hi[col][mt*16+r0] = h4;
            *(short4v*)&U.hvT.lo[col][mt*16+r0] = l4;
        }
    }
    __syncthreads();

    f32x4 acc2[16];
    #pragma unroll
    for (int nt=0;nt<16;++nt){
        int col=nt*16+c15;
        float bv=(col<128)? b_iah[col] : b_oah[col-128];
        acc2[nt]=(f32x4){bv,bv,bv,bv};
    }
    short8v aihi[2],ailo[2],aohi[2],aolo[2];
    {
        const float* Ab = Amat + (size_t)bl*8192 + (size_t)row*128;
        #pragma unroll
        for (int ks=0;ks<2;++ks){
            float4 f0=*(const float4*)(Ab+ks*32+kg);
            float4 f1=*(const float4*)(Ab+ks*32+kg+4);
            float xs[8]={f0.x,f0.y,f0.z,f0.w,f1.x,f1.y,f1.z,f1.w};
            split8(xs,aihi[ks],ailo[ks]);
            float4 g0=*(const float4*)(Ab+64+ks*32+kg);
            float4 g1=*(const float4*)(Ab+64+ks*32+kg+4);
            float ys[8]={g0.x,g0.y,g0.z,g0.w,g1.x,g1.y,g1.z,g1.w};
            split8(ys,aohi[ks],aolo[ks]);
        }
    }
    #pragma unroll
    for (int ks=0;ks<2;++ks){
        #pragma unroll
        for (int nt=0;nt<16;++nt){
            int h=nt*16+c15;
            int m0=ks*32+kg;
            short8v bh=*(const short8v*)&U.hvT.hi[h][m0];
            short8v bl_=*(const short8v*)&U.hvT.lo[h][m0];
            short8v ah=(nt<8)?aihi[ks]:aohi[ks];
            short8v al=(nt<8)?ailo[ks]:aolo[ks];
            acc2[nt]=__builtin_amdgcn_mfma_f32_16x16x32_bf16(ah,bh,acc2[nt],0,0,0);
            acc2[nt]=__builtin_amdgcn_mfma_f32_16x16x32_bf16(al,bh,acc2[nt],0,0,0);
            acc2[nt]=__builtin_amdgcn_mfma_f32_16x16x32_bf16(ah,bl_,acc2[nt],0,0,0);
        }
    }
    __syncthreads();

    {
        #pragma unroll
        for (int nt=0;nt<16;++nt){
            int col=nt*16+c15;
            #pragma unroll
            for (int j=0;j<4;++j)
                U.inp[mt*16+g*4+j][col]=acc2[nt][j];
        }
    }
    __syncthreads();

    {
        #pragma unroll
        for (int ks=0;ks<8;++ks){
            float4 f0=*(const float4*)&U.inp[row][ks*32+kg];
            float4 f1=*(const float4*)&U.inp[row][ks*32+kg+4];
            float xs[8]={f0.x,f0.y,f0.z,f0.w,f1.x,f1.y,f1.z,f1.w};
            short8v h,l; split8(xs,h,l);
            size_t off=((size_t)(bl*4+mt)*8+ks)*512 + lane*8;
            *(short8v*)(inp_hi+off)=h; *(short8v*)(inp_lo+off)=l;
        }
    }
}

// ---------------- K2: gi/gh GEMMs + GRU gate (2 waves per row-tile) ----------------
__global__ __launch_bounds__(512,1) void k_gru(
    const unsigned short* __restrict__ inp_hi, const unsigned short* __restrict__ inp_lo,
    const unsigned short* __restrict__ hid_hi, const unsigned short* __restrict__ hid_lo,
    const unsigned short* __restrict__ wih_hi, const unsigned short* __restrict__ wih_lo,
    const unsigned short* __restrict__ whh_hi, const unsigned short* __restrict__ whh_lo,
    const float* __restrict__ b_ih, const float* __restrict__ b_hh,
    const float* __restrict__ hidden, float* __restrict__ hidnew)
{
    const int t=threadIdx.x, lane=t&63, w=t>>6;
    const int wh = w & 1;
    const int gmt = blockIdx.x*4 + (w>>1);
    const int c15=lane&15, g=lane>>4;

    __shared__ unsigned short wbuf[2][24][1024];

    auto stage=[&](int ks, int buf){
        #pragma unroll
        for (int i=0;i<3;++i){
            int idx=i*512+t;
            int nt=idx>>6, ln=idx&63;
            const unsigned short *sh, *sl;
            if (ks<4){ size_t o=((size_t)(nt*4+ks)*64+ln)*8; sh=whh_hi+o; sl=whh_lo+o; }
            else     { size_t o=((size_t)(nt*8+(ks-4))*64+ln)*8; sh=wih_hi+o; sl=wih_lo+o; }
            *(short8v*)&wbuf[buf][nt][ln*8]     = *(const short8v*)sh;
            *(short8v*)&wbuf[buf][nt][512+ln*8] = *(const short8v*)sl;
        }
    };

    f32x4 agi[12], agh[12];
    #pragma unroll
    for (int j=0;j<12;++j){
        int nt=(j>>2)*8 + wh*4 + (j&3);
        int col=nt*16+c15;
        float bi=b_ih[col], bh=b_hh[col];
        agi[j]=(f32x4){bi,bi,bi,bi};
        agh[j]=(f32x4){bh,bh,bh,bh};
    }

    stage(0,0);
    __syncthreads();
    for (int ks=0; ks<12; ++ks){
        int buf=ks&1;
        if (ks<11) stage(ks+1, buf^1);
        short8v ah, al;
        if (ks<4){
            size_t o=((size_t)gmt*4+ks)*512 + (size_t)lane*8;
            ah=*(const short8v*)(hid_hi+o); al=*(const short8v*)(hid_lo+o);
        } else {
            size_t o=((size_t)gmt*8+(ks-4))*512 + (size_t)lane*8;
            ah=*(const short8v*)(inp_hi+o); al=*(const short8v*)(inp_lo+o);
        }
        if (ks<4){
            #pragma unroll
            for (int j=0;j<12;++j){
                int nt=(j>>2)*8 + wh*4 + (j&3);
                short8v bh=*(const short8v*)&wbuf[buf][nt][lane*8];
                short8v bl_=*(const short8v*)&wbuf[buf][nt][512+lane*8];
                agh[j]=__builtin_amdgcn_mfma_f32_16x16x32_bf16(ah,bh,agh[j],0,0,0);
                agh[j]=__builtin_amdgcn_mfma_f32_16x16x32_bf16(al,bh,agh[j],0,0,0);
                agh[j]=__builtin_amdgcn_mfma_f32_16x16x32_bf16(ah,bl_,agh[j],0,0,0);
            }
        } else {
            #pragma unroll
            for (int j=0;j<12;++j){
                int nt=(j>>2)*8 + wh*4 + (j&3);
                short8v bh=*(const short8v*)&wbuf[buf][nt][lane*8];
                short8v bl_=*(const short8v*)&wbuf[buf][nt][512+lane*8];
                agi[j]=__builtin_amdgcn_mfma_f32_16x16x32_bf16(ah,bh,agi[j],0,0,0);
                agi[j]=__builtin_amdgcn_mfma_f32_16x16x32_bf16(al,bh,agi[j],0,0,0);
                agi[j]=__builtin_amdgcn_mfma_f32_16x16x32_bf16(ah,bl_,agi[j],0,0,0);
            }
        }
        __syncthreads();
    }

    const int r0=gmt*16+g*4;
    #pragma unroll
    for (int sub=0;sub<4;++sub){
        int h=(wh*4+sub)*16+c15;
        #pragma unroll
        for (int j2=0;j2<4;++j2){
            float ir=agi[sub][j2], ii=agi[4+sub][j2], in_=agi[8+sub][j2];
            float hr=agh[sub][j2], hi_=agh[4+sub][j2], hn=agh[8+sub][j2];
            float rg=sigmoidf_(ir+hr), ig=sigmoidf_(ii+hi_);
            float ng=tanhf(in_+rg*hn);
            float ho=hidden[(size_t)(r0+j2)*128+h];
            hidnew[(size_t)(r0+j2)*128+h]=ng+ig*(ho-ng);
        }
    }
}

// ---------------- fused tail: seq(+tanh,l2norm) + q1/q2 + attention + afin -> pA frags ----------------
__global__ __launch_bounds__(256) void k_tail(
    const int* __restrict__ alias, const float* __restrict__ pos,
    const float* __restrict__ hn,
    const unsigned short* __restrict__ lp_hi, const unsigned short* __restrict__ lp_lo,
    const unsigned short* __restrict__ w2_hi, const unsigned short* __restrict__ w2_lo,
    const float* __restrict__ b2,
    const float* __restrict__ W1, const float* __restrict__ b1,
    const float* __restrict__ W3,
    const float* __restrict__ Wt, const float* __restrict__ bt,
    unsigned short* __restrict__ pA_hi, unsigned short* __restrict__ pA_lo)
{
    const int t=threadIdx.x, lane=t&63, w=t>>6, b=blockIdx.x;
    const int c15=lane&15, g=lane>>4;

    __shared__ union { float X[64][260]; float S[64][132]; } U;
    __shared__ int s_alias[64];
    __shared__ float s_q1[128], s_ht[128], s_alpha[64], s_a[128];
    __shared__ int s_last;

    if (t<64) s_alias[t]=alias[b*64+t];
    __syncthreads();
    if (t==0){
        int c=0;
        for (int l=0;l<64;++l) c += (s_alias[l]>0) ? 1 : 0;
        s_last=(c-1)&63;
    }
    #pragma unroll
    for (int c=0;c<8;++c){
        int flat=c*1024+t*4, l=flat>>7, k=flat&127;
        *(float4*)&U.X[l][k] = *(const float4*)(pos + l*128 + k);
        int row=s_alias[l];
        *(float4*)&U.X[l][128+k] = *(const float4*)(hn + (size_t)(b*64+row)*128 + k);
    }
    __syncthreads();

    // ---- Y = tanh(X @ lp), wave w owns rows w*16..w*16+15 ----
    f32x4 acc[8];
    #pragma unroll
    for (int nt=0;nt<8;++nt) acc[nt]=(f32x4){0.f,0.f,0.f,0.f};
    #pragma unroll
    for (int ks=0;ks<8;++ks){
        const float* xp=&U.X[w*16+c15][ks*32+g*8];
        float4 f0=*(const float4*)xp, f1=*(const float4*)(xp+4);
        float xs[8]={f0.x,f0.y,f0.z,f0.w,f1.x,f1.y,f1.z,f1.w};
        short8v ah,al; split8(xs,ah,al);
        #pragma unroll
        for (int nt=0;nt<8;++nt){
            size_t off=((size_t)(nt*8+ks)*64+lane)*8;
            short8v bh=*(const short8v*)(lp_hi+off);
            short8v bl_=*(const short8v*)(lp_lo+off);
            acc[nt]=__builtin_amdgcn_mfma_f32_16x16x32_bf16(ah,bh,acc[nt],0,0,0);
            acc[nt]=__builtin_amdgcn_mfma_f32_16x16x32_bf16(al,bh,acc[nt],0,0,0);
            acc[nt]=__builtin_amdgcn_mfma_f32_16x16x32_bf16(ah,bl_,acc[nt],0,0,0);
        }
    }
    // tanh then row-sumsq (reduce across the 16 lanes of each quarter-wave)
    float pj[4]={0.f,0.f,0.f,0.f};
    #pragma unroll
    for (int nt=0;nt<8;++nt){
        #pragma unroll
        for (int j=0;j<4;++j){
            float v=tanhf(acc[nt][j]);
            acc[nt][j]=v;
            pj[j]=fmaf(v,v,pj[j]);
        }
    }
    #pragma unroll
    for (int m=1;m<16;m<<=1){
        #pragma unroll
        for (int j=0;j<4;++j) pj[j]+=__shfl_xor(pj[j],m,64);
    }
    float rn[4];
    #pragma unroll
    for (int j=0;j<4;++j) rn[j]=rsqrtf(pj[j]);

    __syncthreads();   // done reading U.X, reuse as U.S
    #pragma unroll
    for (int nt=0;nt<8;++nt){
        #pragma unroll
        for (int j=0;j<4;++j)
            U.S[w*16+g*4+j][nt*16+c15]=acc[nt][j]*rn[j];
    }
    __syncthreads();

    if (t<128) s_ht[t]=U.S[s_last][t];
    __syncthreads();

    // ---- q1 = ht @ W1^T + b1 (threads 0..127) ----
    if (t<128){
        float o=b1[t];
        const float* wr=W1+(size_t)t*128;
        #pragma unroll 8
        for (int k=0;k<128;k+=4){
            float4 wv=*(const float4*)(wr+k);
            o += s_ht[k]*wv.x + s_ht[k+1]*wv.y + s_ht[k+2]*wv.z + s_ht[k+3]*wv.w;
        }
        s_q1[t]=o;
    }

    // ---- q2 = seq @ W2^T + b2 (MFMA, all waves) ----
    f32x4 acc2[8];
    #pragma unroll
    for (int nt=0;nt<8;++nt){
        float bv=b2[nt*16+c15];
        acc2[nt]=(f32x4){bv,bv,bv,bv};
    }
    #pragma unroll
    for (int ks=0;ks<4;++ks){
        const float* sp=&U.S[w*16+c15][ks*32+g*8];
        float4 f0=*(const float4*)sp, f1=*(const float4*)(sp+4);
        float xs[8]={f0.x,f0.y,f0.z,f0.w,f1.x,f1.y,f1.z,f1.w};
        short8v ah,al; split8(xs,ah,al);
        #pragma unroll
        for (int nt=0;nt<8;++nt){
            size_t off=((size_t)(nt*4+ks)*64+lane)*8;
            short8v bh=*(const short8v*)(w2_hi+off);
            short8v bl_=*(const short8v*)(w2_lo+off);
            acc2[nt]=__builtin_amdgcn_mfma_f32_16x16x32_bf16(ah,bh,acc2[nt],0,0,0);
            acc2[nt]=__builtin_amdgcn_mfma_f32_16x16x32_bf16(al,bh,acc2[nt],0,0,0);
            acc2[nt]=__builtin_amdgcn_mfma_f32_16x16x32_bf16(ah,bl_,acc2[nt],0,0,0);
        }
    }
    __syncthreads();   // s_q1 ready

    // ---- alpha[l] = sum_h sigmoid(q1[h]+q2[l][h]) * W3[h], masked ----
    {
        float pa[4]={0.f,0.f,0.f,0.f};
        #pragma unroll
        for (int nt=0;nt<8;++nt){
            int col=nt*16+c15;
            float w3v=W3[col];
            #pragma unroll
            for (int j=0;j<4;++j)
                pa[j]=fmaf(sigmoidf_(s_q1[col]+acc2[nt][j]), w3v, pa[j]);
        }
        #pragma unroll
        for (int m=1;m<16;m<<=1){
            #pragma unroll
            for (int j=0;j<4;++j) pa[j]+=__shfl_xor(pa[j],m,64);
        }
        if (c15==0){
            #pragma unroll
            for (int j=0;j<4;++j){
                int l=w*16+g*4+j;
                s_alpha[l]=(s_alias[l]>0)? pa[j] : 0.f;
            }
        }
    }
    __syncthreads();

    // ---- a[h] = sum_l alpha[l]*seq[l][h] ----
    if (t<128){
        float a_=0.f;
        #pragma unroll 8
        for (int l=0;l<64;++l) a_=fmaf(s_alpha[l],U.S[l][t],a_);
        s_a[t]=a_;
    }
    __syncthreads();

    // ---- afin = [a|ht] @ Wt^T + bt, emit pred A-fragments ----
    if (t<128){
        float o=bt[t];
        const float* wr=Wt+(size_t)t*256;
        #pragma unroll 8
        for (int k=0;k<128;k+=4){
            float4 wv=*(const float4*)(wr+k);
            o += s_a[k]*wv.x + s_a[k+1]*wv.y + s_a[k+2]*wv.z + s_a[k+3]*wv.w;
        }
        #pragma unroll 8
        for (int k=0;k<128;k+=4){
            float4 wv=*(const float4*)(wr+128+k);
            o += s_ht[k]*wv.x + s_ht[k+1]*wv.y + s_ht[k+2]*wv.z + s_ht[k+3]*wv.w;
        }
        unsigned short hi,lo; split_bf16(o,hi,lo);
        int mt=b>>4, r15=b&15;
        int ks=t>>5, gg=(t>>3)&3, e=t&7;
        int lz=gg*16+r15;
        size_t off=(((size_t)mt*4+ks)*64+lz)*8+e;
        pA_hi[off]=hi; pA_lo[off]=lo;
    }
}

// ---------------- pred = 16 * afin @ emb[1:]^T (2-product split, frag emb) ----------------
__global__ __launch_bounds__(256) void k_pred_mfma(
    const unsigned short* __restrict__ Ahi, const unsigned short* __restrict__ Alo,
    const unsigned short* __restrict__ Ebf, float* __restrict__ outp)
{
    const int t=threadIdx.x, lane=t&63, w=t>>6;
    const int vt=blockIdx.x, cb=vt*64;
    const int c15=lane&15, g=lane>>4;

    __shared__ float s_out[4][16][68];

    short8v B[16];
    #pragma unroll
    for (int q=0;q<16;++q){
        size_t off = (((size_t)vt*16 + q)*64 + lane)*8;
        B[q] = *(const short8v*)(Ebf + off);
    }

    for (int mt=w; mt<32; mt+=4){
        short8v ahi[4], alo[4];
        #pragma unroll
        for (int ks=0;ks<4;++ks){
            size_t off=((size_t)(mt*4+ks)*64+lane)*8;
            ahi[ks]=*(const short8v*)(Ahi+off);
            alo[ks]=*(const short8v*)(Alo+off);
        }
        #pragma unroll
        for (int nt=0;nt<4;++nt){
            f32x4 acc={0.f,0.f,0.f,0.f};
            #pragma unroll
            for (int ks=0;ks<4;++ks){
                acc=__builtin_amdgcn_mfma_f32_16x16x32_bf16(ahi[ks],B[nt*4+ks],acc,0,0,0);
                acc=__builtin_amdgcn_mfma_f32_16x16x32_bf16(alo[ks],B[nt*4+ks],acc,0,0,0);
            }
            #pragma unroll
            for (int j=0;j<4;++j) s_out[w][g*4+j][nt*16+c15] = 16.0f*acc[j];
        }
        #pragma unroll
        for (int rep=0;rep<4;++rep){
            int f4 = rep*64 + lane;
            int r = f4 >> 4, c4 = (f4 & 15)*4;
            float4 o = *(float4*)&s_out[w][r][c4];
            int col = cb + c4;
            size_t rowoff = (size_t)(mt*16 + r)*NVOCAB;
            if (col + 3 < NVOCAB){
                *(float4*)(outp + rowoff + col) = o;
            } else {
                float vals[4]={o.x,o.y,o.z,o.w};
                #pragma unroll
                for (int cc=0;cc<4;++cc)
                    if (col+cc < NVOCAB) outp[rowoff + col + cc] = vals[cc];
            }
        }
    }
}

extern "C" void kernel_launch(void* const* d_in, const int* in_sizes, int n_in,
                              void* d_out, int out_size, void* d_ws, size_t ws_size,
                              hipStream_t stream)
{
    const int*   items = (const int*)  d_in[0];
    const float* Amat  = (const float*)d_in[1];
    const int*   alias = (const int*)  d_in[2];
    const float* emb   = (const float*)d_in[3];
    const float* pos   = (const float*)d_in[4];
    const float* lp    = (const float*)d_in[5];
    const float* w_ih  = (const float*)d_in[6];
    const float* w_hh  = (const float*)d_in[7];
    const float* b_ih  = (const float*)d_in[8];
    const float* b_hh  = (const float*)d_in[9];
    const float* b_iah = (const float*)d_in[10];
    const float* b_oah = (const float*)d_in[11];
    const float* W_in  = (const float*)d_in[12];
    const float* b_in  = (const float*)d_in[13];
    const float* W_out = (const float*)d_in[14];
    const float* b_out = (const float*)d_in[15];
    const float* W1    = (const float*)d_in[16];
    const float* b1    = (const float*)d_in[17];
    const float* W2    = (const float*)d_in[18];
    const float* b2    = (const float*)d_in[19];
    const float* W3    = (const float*)d_in[20];
    const float* Wt    = (const float*)d_in[21];
    const float* bt    = (const float*)d_in[22];
    float* outp = (float*)d_out;

    // ---- workspace carve ----
    float* wsf = (float*)d_ws;
    size_t o = 0;
    float* hidden = wsf + o;               o += 4194304;
    float* hidnew = wsf + o;               o += 4194304;
    unsigned short* us = (unsigned short*)(wsf + o);
    size_t uo = 0;
    unsigned short* wo_hi  = us + uo; uo += 32768;
    unsigned short* wo_lo  = us + uo; uo += 32768;
    unsigned short* wih_hi = us + uo; uo += 98304;
    unsigned short* wih_lo = us + uo; uo += 98304;
    unsigned short* whh_hi = us + uo; uo += 49152;
    unsigned short* whh_lo = us + uo; uo += 49152;
    unsigned short* lp_hi  = us + uo; uo += 32768;
    unsigned short* lp_lo  = us + uo; uo += 32768;
    unsigned short* w2_hi  = us + uo; uo += 16384;
    unsigned short* w2_lo  = us + uo; uo += 16384;
    unsigned short* pA_hi  = us + uo; uo += 65536;
    unsigned short* pA_lo  = us + uo; uo += 65536;
    unsigned short* hidf_hi= us + uo; uo += 4194304;
    unsigned short* hidf_lo= us + uo; uo += 4194304;
    unsigned short* inpf_hi= us + uo; uo += 8388608;
    unsigned short* inpf_lo= us + uo; uo += 8388608;
    unsigned short* Ebf    = us + uo; uo += 12804096;

    k_prep_wfrag<<<112, 256, 0, stream>>>(W_in, W_out, w_ih, w_hh, lp, W2,
                                          wo_hi, wo_lo, wih_hi, wih_lo, whh_hi, whh_lo,
                                          lp_hi, lp_lo, w2_hi, w2_lo);
    k_prep_embf<<<6252, 256, 0, stream>>>(emb, Ebf);
    k_gnn1<<<512, 256, 0, stream>>>(items, Amat, emb, b_in, b_out, b_iah, b_oah,
                                    wo_hi, wo_lo, hidden, hidf_hi, hidf_lo, inpf_hi, inpf_lo);
    k_gru<<<512, 512, 0, stream>>>(inpf_hi, inpf_lo, hidf_hi, hidf_lo,
                                   wih_hi, wih_lo, whh_hi, whh_lo, b_ih, b_hh, hidden, hidnew);
    k_tail<<<512, 256, 0, stream>>>(alias, pos, hidnew,
                                    lp_hi, lp_lo, w2_hi, w2_lo, b2,
                                    W1, b1, W3, Wt, bt, pA_hi, pA_lo);
    k_pred_mfma<<<1563, 256, 0, stream>>>(pA_hi, pA_lo, Ebf, outp);
}